// Round 11
// baseline (1040.750 us; speedup 1.0000x reference)
//
#include <hip/hip_runtime.h>
#include <hip/hip_bf16.h>
#include <math.h>

typedef __attribute__((ext_vector_type(8))) short bf16x8;
typedef __attribute__((ext_vector_type(4))) short bf16x4;
typedef __attribute__((ext_vector_type(4))) float f32x4;
typedef __hip_bfloat16 bf16;

#define NH 12
#define HD 32
#define NWIN 2048
#define NTOK 100352

typedef __attribute__((address_space(3))) const void cv3;

#define STR2(x) #x
#define DSR(dst, base, OFF)                                                  \
  asm volatile("ds_read_b128 %0, %1 offset:" STR2(OFF)                       \
               : "=v"(dst) : "v"(base))

__device__ inline float wave_sum(float v) {
#pragma unroll
  for (int off = 32; off; off >>= 1) v += __shfl_xor(v, off);
  return v;
}

__device__ inline void load_lds16(const bf16* g, bf16* l) {
  __builtin_amdgcn_global_load_lds((const __attribute__((address_space(1))) void*)g,
                                   (__attribute__((address_space(3))) void*)l, 16, 0, 0);
}

__device__ inline short bfbits(float f) {
  bf16 h = __float2bfloat16(f);
  return *(short*)&h;
}

// ---------------- weight cast + transpose: in (K x N) f32 -> out (N x K) bf16
__global__ __launch_bounds__(256) void cast_transpose(const float* __restrict__ in,
                                                      bf16* __restrict__ out, int K, int N) {
  int e = blockIdx.x * 256 + threadIdx.x;
  if (e >= K * N) return;
  int n = e / K, k = e - n * K;
  out[e] = __float2bfloat16(in[k * N + n]);
}

// ---------------- bias+mask table: tbl[cls][h][row][64] (cols 49..63 = -1e30)
__global__ __launch_bounds__(256) void build_bias(const float* __restrict__ rel,
                                                  float* __restrict__ tbl) {
  int e = blockIdx.x * 256 + threadIdx.x;
  if (e >= 4 * 12 * 49 * 64) return;
  int col = e & 63; int t = e >> 6;
  int row = t % 49; t /= 49;
  int h = t % 12; int cls = t / 12;
  float v;
  if (col >= 49) {
    v = -1e30f;
  } else {
    int py = row / 7, px = row - py * 7;
    int qy = col / 7, qx = col - qy * 7;
    int ridx = (py - qy + 6) * 13 + (px - qx + 6);
    v = rel[ridx * 12 + h];
    int wy7 = cls >> 1, wx7 = cls & 1;
    int ly_r = wy7 ? (py < 4 ? 1 : 2) : 0;
    int lx_r = wx7 ? (px < 4 ? 1 : 2) : 0;
    int ly_c = wy7 ? (qy < 4 ? 1 : 2) : 0;
    int lx_c = wx7 ? (qx < 4 ? 1 : 2) : 0;
    if ((ly_r * 3 + lx_r) != (ly_c * 3 + lx_c)) v += -100.0f;
  }
  tbl[e] = v;
}

// ---------------- LayerNorm. MODE 0: LN1 + roll(-3,-3) + window partition (src mapped)
//                  MODE 1: LN2 straight rows
template <int MODE>
__global__ __launch_bounds__(256) void ln_kernel(const float* __restrict__ x,
                                                 const float* __restrict__ g,
                                                 const float* __restrict__ be,
                                                 bf16* __restrict__ out) {
  int wv = threadIdx.x >> 6, lane = threadIdx.x & 63;
  int t = blockIdx.x * 4 + wv;
  size_t src;
  if (MODE == 0) {
    int w = t / 49, n = t - w * 49;
    int b = w >> 6, wi = w & 63;
    int wy = wi >> 3, wx = wi & 7;
    int py = n / 7, px = n - py * 7;
    int rr = wy * 7 + py, cc = wx * 7 + px;
    int ro = rr + 3; if (ro >= 56) ro -= 56;
    int co = cc + 3; if (co >= 56) co -= 56;
    src = (size_t)b * 3136 + ro * 56 + co;
  } else {
    src = (size_t)t;
  }
  const float2* row2 = (const float2*)(x + src * 384);
  float2 v[3]; float s = 0.f;
#pragma unroll
  for (int j = 0; j < 3; ++j) { v[j] = row2[lane + 64 * j]; s += v[j].x + v[j].y; }
  s = wave_sum(s);
  float mu = s * (1.f / 384.f);
  float q = 0.f;
#pragma unroll
  for (int j = 0; j < 3; ++j) {
    float dx = v[j].x - mu, dy = v[j].y - mu;
    q += dx * dx + dy * dy;
  }
  q = wave_sum(q);
  float rs = rsqrtf(q * (1.f / 384.f) + 1e-5f);
  uint* o = (uint*)(out + (size_t)t * 384);
  const float2* g2 = (const float2*)g;
  const float2* b2 = (const float2*)be;
#pragma unroll
  for (int j = 0; j < 3; ++j) {
    int c2 = lane + 64 * j;
    float2 gg = g2[c2], bb = b2[c2];
    float ox = (v[j].x - mu) * rs * gg.x + bb.x;
    float oy = (v[j].y - mu) * rs * gg.y + bb.y;
    o[c2] = (uint)(unsigned short)bfbits(ox) | ((uint)(unsigned short)bfbits(oy) << 16);
  }
}

// ---------------- GEMM (R8 structure, best measured): C = A(M x K) * B^T. Tile 256x128,
// 8 waves (4M x 2N, wave-tile 64x64), BK=64, 3-stage LDS ring, 2-deep prefetch, counted
// vmcnt(6). Inline-asm ds_read_b128 + rule-18 fences. XOR-swizzled LDS. Swapped-operand
// MFMA -> thread holds 4 consecutive C-cols. Bijective chunked XCD swizzle.
// EPI: 1=proj+residual+reverse, 2=GELU->h1, 3=out=acc+b2+x1 -> d_out
template <int EPI>
__global__ __launch_bounds__(512, 2) void gemm_bf16(const bf16* __restrict__ A,
                                                    const bf16* __restrict__ BT,
                                                    int K, int NCOL, int row0,
                                                    const float* __restrict__ bias,
                                                    const float* __restrict__ extra,
                                                    void* __restrict__ outp) {
  __shared__ __align__(16) bf16 As[3][256 * 64];   // 3 x 32 KB
  __shared__ __align__(16) bf16 Bs[3][128 * 64];   // 3 x 16 KB  (total 144 KB)
  int tid = threadIdx.x;
  int lane = tid & 63, wv = tid >> 6;              // wv 0..7
  int wr = wv >> 1, wc = wv & 1;
  int lr = lane & 15, lg = lane >> 4;

  int nwg = gridDim.x;
  int bid = blockIdx.x;
  int xcd = bid & 7, li = bid >> 3;
  int qq = nwg >> 3, rr8 = nwg & 7;
  int start = xcd * qq + (xcd < rr8 ? xcd : rr8);
  int lin = start + li;
  int brow = lin / NCOL, bcol = lin - brow * NCOL;

  const bf16* Ab = A + (size_t)brow * 256 * K;
  const bf16* Bb = BT + (size_t)bcol * 128 * K;

  int srow = lane >> 3;
  int scol = ((lane & 7) * 8) ^ (srow << 3);
  const bf16* aS = Ab + (size_t)(wv * 32 + srow) * K + scol;
  const bf16* bS = Bb + (size_t)(wv * 16 + srow) * K + scol;

  f32x4 acc[4][4] = {};
  int nk = K >> 6;
  int xorm = (lr & 7) << 3;

#define STAGE(buf)                                                        \
  {                                                                       \
    _Pragma("unroll") for (int c = 0; c < 4; ++c)                         \
        load_lds16(aS + (size_t)c * 8 * K, &As[buf][wv * 2048 + c * 512]);\
    _Pragma("unroll") for (int c = 0; c < 2; ++c)                         \
        load_lds16(bS + (size_t)c * 8 * K, &Bs[buf][wv * 1024 + c * 512]);\
    aS += 64; bS += 64;                                                   \
  }

  STAGE(0);
  STAGE(1);
  asm volatile("s_waitcnt vmcnt(6)" ::: "memory");
  __builtin_amdgcn_s_barrier();

  for (int kk = 0; kk < nk; ++kk) {
    int cur = kk % 3;
    if (kk + 2 < nk) STAGE((kk + 2) % 3);
    int k0 = (lg * 8) ^ xorm;
    int k1 = (32 + lg * 8) ^ xorm;
    cv3* pA0 = (cv3*)&As[cur][(wr * 64 + lr) * 64 + k0];
    cv3* pB0 = (cv3*)&Bs[cur][(wc * 64 + lr) * 64 + k0];
    cv3* pA1 = (cv3*)&As[cur][(wr * 64 + lr) * 64 + k1];
    cv3* pB1 = (cv3*)&Bs[cur][(wc * 64 + lr) * 64 + k1];
    bf16x8 a0[4], b0[4], a1[4], b1[4];
    DSR(a0[0], pA0, 0); DSR(a0[1], pA0, 2048); DSR(a0[2], pA0, 4096); DSR(a0[3], pA0, 6144);
    DSR(b0[0], pB0, 0); DSR(b0[1], pB0, 2048); DSR(b0[2], pB0, 4096); DSR(b0[3], pB0, 6144);
    asm volatile("s_waitcnt lgkmcnt(0)" ::: "memory");
    __builtin_amdgcn_sched_barrier(0);
    DSR(a1[0], pA1, 0); DSR(a1[1], pA1, 2048); DSR(a1[2], pA1, 4096); DSR(a1[3], pA1, 6144);
    DSR(b1[0], pB1, 0); DSR(b1[1], pB1, 2048); DSR(b1[2], pB1, 4096); DSR(b1[3], pB1, 6144);
    __builtin_amdgcn_sched_barrier(0);
#pragma unroll
    for (int i = 0; i < 4; ++i)
#pragma unroll
      for (int j = 0; j < 4; ++j)
        acc[i][j] = __builtin_amdgcn_mfma_f32_16x16x32_bf16(b0[j], a0[i], acc[i][j], 0, 0, 0);
    asm volatile("s_waitcnt lgkmcnt(0)" ::: "memory");
    __builtin_amdgcn_sched_barrier(0);
#pragma unroll
    for (int i = 0; i < 4; ++i)
#pragma unroll
      for (int j = 0; j < 4; ++j)
        acc[i][j] = __builtin_amdgcn_mfma_f32_16x16x32_bf16(b1[j], a1[i], acc[i][j], 0, 0, 0);
    if (kk + 1 < nk) {
      if (kk + 2 < nk)
        asm volatile("s_waitcnt vmcnt(6)" ::: "memory");
      else
        asm volatile("s_waitcnt vmcnt(0)" ::: "memory");
      __builtin_amdgcn_s_barrier();
    }
  }
#undef STAGE

  float4 bias4[4];
#pragma unroll
  for (int j = 0; j < 4; ++j)
    bias4[j] = *(const float4*)(bias + bcol * 128 + wc * 64 + j * 16 + lg * 4);

#pragma unroll
  for (int i = 0; i < 4; ++i) {
    int lrow = brow * 256 + wr * 64 + i * 16 + lr;
    int grow = row0 + lrow;
    size_t tok = 0;
    if (EPI == 1) {
      int w_ = grow / 49, n_ = grow - (grow / 49) * 49;
      int b_ = w_ >> 6, wi = w_ & 63;
      int wy = wi >> 3, wx = wi & 7;
      int py = n_ / 7, px = n_ - py * 7;
      int r2 = wy * 7 + py, c2 = wx * 7 + px;
      int ro = r2 + 3; if (ro >= 56) ro -= 56;
      int co = c2 + 3; if (co >= 56) co -= 56;
      tok = (size_t)b_ * 3136 + ro * 56 + co;
    }
#pragma unroll
    for (int j = 0; j < 4; ++j) {
      int col = bcol * 128 + wc * 64 + j * 16 + lg * 4;
      float v0 = acc[i][j][0] + bias4[j].x;
      float v1 = acc[i][j][1] + bias4[j].y;
      float v2 = acc[i][j][2] + bias4[j].z;
      float v3 = acc[i][j][3] + bias4[j].w;
      if (EPI == 1) {
        size_t oidx = tok * 384 + col;
        float4 e = *(const float4*)(extra + oidx);
        float4 o = {v0 + e.x, v1 + e.y, v2 + e.z, v3 + e.w};
        *(float4*)((float*)outp + oidx) = o;
      } else if (EPI == 2) {
        float g0 = 0.5f * v0 * (1.0f + erff(v0 * 0.70710678118654752f));
        float g1 = 0.5f * v1 * (1.0f + erff(v1 * 0.70710678118654752f));
        float g2 = 0.5f * v2 * (1.0f + erff(v2 * 0.70710678118654752f));
        float g3 = 0.5f * v3 * (1.0f + erff(v3 * 0.70710678118654752f));
        bf16x4 p = {bfbits(g0), bfbits(g1), bfbits(g2), bfbits(g3)};
        *(bf16x4*)((bf16*)outp + (size_t)lrow * 1536 + col) = p;
      } else {
        size_t oidx = (size_t)grow * 384 + col;
        float4 e = *(const float4*)(extra + oidx);
        float4 o = {v0 + e.x, v1 + e.y, v2 + e.z, v3 + e.w};
        *(float4*)((float*)outp + oidx) = o;
      }
    }
  }
}

// ---------------- FUSED QKV-projection + windowed attention.
// One block per window (256 thr, 4 waves x 3 heads). A-tile (64x384, rows>=49 zero) staged
// once into XOR-swizzled LDS; per head, Q/K/V = A*W computed with W b-frags read directly
// from L2-resident wqkvT; Q/K/V round-trip through per-wave padded LDS (Q,K stride 40;
// Vt stride 72; P stride 72 overlays Q+K); then S=QK^T + table-softmax + PV as before.
// Writes attn_out in place over xw (block-local rows only). One barrier total.
__global__ __launch_bounds__(256) void fused_qkv_attn(bf16* __restrict__ xw,
                                                      const bf16* __restrict__ wT,
                                                      const float* __restrict__ bqkv,
                                                      const float* __restrict__ tbl) {
  __shared__ __align__(16) bf16 At[64 * 384];   // 48 KB, XOR-swizzled (granule ^= row&7)
  __shared__ __align__(16) bf16 Scr[4][7424];   // per-wave: Q[64*40] K[64*40] Vt[32*72]
  int tid = threadIdx.x;
  int lane = tid & 63, wv = tid >> 6;
  int lr = lane & 15, lg = lane >> 4;
  int w = blockIdx.x;
  int wi = w & 63, wy = wi >> 3, wx = wi & 7;
  int cls = ((wy == 7) ? 2 : 0) | ((wx == 7) ? 1 : 0);
  const float scale = 0.17677669529663689f;

  // stage A-tile: rows w*49..w*49+48 of xw; rows 49..63 zero; swizzled granule
  bf16* xrow = xw + (size_t)w * 49 * 384;
  for (int idx = tid; idx < 64 * 48; idx += 256) {
    int r = idx / 48, g = idx - r * 48;
    bf16x8 v = {};
    if (r < 49) v = *(const bf16x8*)(xrow + r * 384 + g * 8);
    *(bf16x8*)(&At[r * 384 + ((g ^ (r & 7)) << 3)]) = v;
  }
  __syncthreads();

  bf16* Q  = &Scr[wv][0];      // stride 40
  bf16* Kl = &Scr[wv][2560];   // stride 40
  bf16* Vt = &Scr[wv][5120];   // stride 72 (32 rows)
  bf16* Pl = &Scr[wv][0];      // stride 72 (64 rows; overlays Q+K)

  int axor = (lr & 7) << 3;

  for (int hh = 0; hh < 3; ++hh) {
    int h = wv + hh * 4;
    // ---- Q/K/V = A * W (+bias) ----
#pragma unroll
    for (int mat = 0; mat < 3; ++mat) {
      int cb = mat * 384 + h * 32;
      const bf16* wb = wT + (size_t)(cb + lr) * 384 + lg * 8;
      f32x4 acc[4][2] = {};
#pragma unroll
      for (int kk = 0; kk < 12; ++kk) {
        int k0 = kk * 32;
        bf16x8 b0 = *(const bf16x8*)(wb + k0);
        bf16x8 b1 = *(const bf16x8*)(wb + 16 * 384 + k0);
        int ko = (k0 + lg * 8) ^ axor;
#pragma unroll
        for (int m = 0; m < 4; ++m) {
          bf16x8 a = *(const bf16x8*)(&At[(m * 16 + lr) * 384 + ko]);
          acc[m][0] = __builtin_amdgcn_mfma_f32_16x16x32_bf16(a, b0, acc[m][0], 0, 0, 0);
          acc[m][1] = __builtin_amdgcn_mfma_f32_16x16x32_bf16(a, b1, acc[m][1], 0, 0, 0);
        }
      }
      float bia0 = bqkv[cb + lr], bia1 = bqkv[cb + 16 + lr];
#pragma unroll
      for (int m = 0; m < 4; ++m)
#pragma unroll
        for (int n = 0; n < 2; ++n)
#pragma unroll
          for (int r = 0; r < 4; ++r) {
            int row = m * 16 + lg * 4 + r;
            int col = n * 16 + lr;
            float v = acc[m][n][r] + (n ? bia1 : bia0);
            if (mat == 2) Vt[col * 72 + row] = __float2bfloat16(v);
            else if (mat == 0) Q[row * 40 + col] = __float2bfloat16(v);
            else Kl[row * 40 + col] = __float2bfloat16(v);
          }
    }

    // ---- S = Q K^T ----
    bf16x8 qa[4], kb[4];
#pragma unroll
    for (int t = 0; t < 4; ++t) {
      qa[t] = *(const bf16x8*)(&Q[(t * 16 + lr) * 40 + lg * 8]);
      kb[t] = *(const bf16x8*)(&Kl[(t * 16 + lr) * 40 + lg * 8]);
    }
    f32x4 S[4][4] = {};
#pragma unroll
    for (int i = 0; i < 4; ++i)
#pragma unroll
      for (int j = 0; j < 4; ++j)
        S[i][j] = __builtin_amdgcn_mfma_f32_16x16x32_bf16(qa[i], kb[j], S[i][j], 0, 0, 0);

    // ---- softmax with bias table; P -> LDS (overlays Q,K) ----
    const float* tb = tbl + (size_t)(cls * 12 + h) * 49 * 64;
#pragma unroll
    for (int i = 0; i < 4; ++i) {
#pragma unroll
      for (int r = 0; r < 4; ++r) {
        int row = i * 16 + lg * 4 + r;
        const float* trow = tb + (row < 49 ? row : 0) * 64;
        float sv[4]; float m = -1e30f;
#pragma unroll
        for (int j = 0; j < 4; ++j) {
          float s = S[i][j][r] * scale + trow[j * 16 + lr];
          sv[j] = s;
          m = fmaxf(m, s);
        }
        m = fmaxf(m, __shfl_xor(m, 1));
        m = fmaxf(m, __shfl_xor(m, 2));
        m = fmaxf(m, __shfl_xor(m, 4));
        m = fmaxf(m, __shfl_xor(m, 8));
        float ev[4]; float sum = 0.f;
#pragma unroll
        for (int j = 0; j < 4; ++j) { ev[j] = __expf(sv[j] - m); sum += ev[j]; }
        sum += __shfl_xor(sum, 1);
        sum += __shfl_xor(sum, 2);
        sum += __shfl_xor(sum, 4);
        sum += __shfl_xor(sum, 8);
        float inv = 1.0f / sum;
#pragma unroll
        for (int j = 0; j < 4; ++j)
          Pl[row * 72 + j * 16 + lr] = __float2bfloat16(ev[j] * inv);
      }
    }

    // ---- O = P * V (Vt is V^T: [d][token], stride 72) ----
    bf16x8 vb[2][2];
#pragma unroll
    for (int kt = 0; kt < 2; ++kt)
#pragma unroll
      for (int cj = 0; cj < 2; ++cj)
        vb[kt][cj] = *(const bf16x8*)(&Vt[(cj * 16 + lr) * 72 + kt * 32 + lg * 8]);
    f32x4 O[4][2] = {};
#pragma unroll
    for (int i = 0; i < 4; ++i) {
#pragma unroll
      for (int kt = 0; kt < 2; ++kt) {
        bf16x8 pa = *(const bf16x8*)(&Pl[(i * 16 + lr) * 72 + kt * 32 + lg * 8]);
#pragma unroll
        for (int cj = 0; cj < 2; ++cj)
          O[i][cj] = __builtin_amdgcn_mfma_f32_16x16x32_bf16(pa, vb[kt][cj], O[i][cj], 0, 0, 0);
      }
    }
#pragma unroll
    for (int i = 0; i < 4; ++i)
#pragma unroll
      for (int cj = 0; cj < 2; ++cj)
#pragma unroll
        for (int r = 0; r < 4; ++r) {
          int n = i * 16 + lg * 4 + r;
          if (n < 49)
            xw[((size_t)w * 49 + n) * 384 + h * 32 + cj * 16 + lr] =
                __float2bfloat16(O[i][cj][r]);
        }
  }
}

extern "C" void kernel_launch(void* const* d_in, const int* in_sizes, int n_in,
                              void* d_out, int out_size, void* d_ws, size_t ws_size,
                              hipStream_t stream) {
  (void)in_sizes; (void)n_in; (void)out_size;
  const float* x     = (const float*)d_in[0];
  const float* g1    = (const float*)d_in[1];
  const float* be1   = (const float*)d_in[2];
  const float* w_qkv = (const float*)d_in[3];
  const float* b_qkv = (const float*)d_in[4];
  const float* rel   = (const float*)d_in[5];
  const float* w_pr  = (const float*)d_in[6];
  const float* b_pr  = (const float*)d_in[7];
  const float* g2    = (const float*)d_in[8];
  const float* be2   = (const float*)d_in[9];
  const float* w1    = (const float*)d_in[10];
  const float* b1    = (const float*)d_in[11];
  const float* w2    = (const float*)d_in[12];
  const float* b2    = (const float*)d_in[13];
  float* out = (float*)d_out;

  if (ws_size < 390070272u) return;  // layout below needs ~318 MiB

  char* ws = (char*)d_ws;
  bf16* wqkvT = (bf16*)(ws);                     // 1152 x 384
  bf16* wprT  = (bf16*)(ws + 884736);            // 384 x 384
  bf16* w1T   = (bf16*)(ws + 1179648);           // 1536 x 384
  bf16* w2T   = (bf16*)(ws + 2359296);           // 384 x 1536
  float* btbl = (float*)(ws + 3538944);          // 4 x 12 x 49 x 64 f32 (602 KB)
  bf16* xw    = (bf16*)(ws + (4u << 20));        // 100352 x 384 bf16 (LN1 out / attn out)
  bf16* m_in  = (bf16*)(ws + (84u << 20));       // 100352 x 384 bf16 (LN2 out)
  bf16* h1    = (bf16*)(ws + (164u << 20));      // 50176 x 1536 bf16 chunk

  cast_transpose<<<dim3((442368 + 255) / 256), 256, 0, stream>>>(w_qkv, wqkvT, 384, 1152);
  cast_transpose<<<dim3((147456 + 255) / 256), 256, 0, stream>>>(w_pr, wprT, 384, 384);
  cast_transpose<<<dim3((589824 + 255) / 256), 256, 0, stream>>>(w1, w1T, 384, 1536);
  cast_transpose<<<dim3((589824 + 255) / 256), 256, 0, stream>>>(w2, w2T, 1536, 384);

  build_bias<<<dim3((4 * 12 * 49 * 64 + 255) / 256), 256, 0, stream>>>(rel, btbl);

  ln_kernel<0><<<dim3(NTOK / 4), 256, 0, stream>>>(x, g1, be1, xw);

  fused_qkv_attn<<<dim3(NWIN), 256, 0, stream>>>(xw, wqkvT, b_qkv, btbl);

  // proj: 392 x 3 = 1176
  gemm_bf16<1><<<dim3(1176), 512, 0, stream>>>(xw, wprT, 384, 3, 0, b_pr, x, (void*)out);

  ln_kernel<1><<<dim3(NTOK / 4), 256, 0, stream>>>(out, g2, be2, m_in);

  for (int c = 0; c < 2; ++c) {
    // MLP1: 196 x 12 = 2352
    gemm_bf16<2><<<dim3(2352), 512, 0, stream>>>(m_in + (size_t)c * 50176 * 384, w1T, 384,
                                                 12, c * 50176, b1, nullptr, (void*)h1);
    // MLP2: 196 x 3 = 588
    gemm_bf16<3><<<dim3(588), 512, 0, stream>>>(h1, w2T, 1536, 3, c * 50176, b2, out,
                                                (void*)out);
  }
}

// Round 12
// 989.134 us; speedup vs baseline: 1.0522x; 1.0522x over previous
//
#include <hip/hip_runtime.h>
#include <hip/hip_bf16.h>
#include <math.h>

typedef __attribute__((ext_vector_type(8))) short bf16x8;
typedef __attribute__((ext_vector_type(4))) short bf16x4;
typedef __attribute__((ext_vector_type(4))) float f32x4;
typedef __hip_bfloat16 bf16;

#define NH 12
#define HD 32
#define NPAD 64
#define NWIN 2048
#define NTOK 100352
#define HBLK (NPAD*HD)
#define WBLK (3*NH*HBLK)

typedef __attribute__((address_space(3))) const void cv3;

#define STR2(x) #x
#define DSR(dst, base, OFF)                                                  \
  asm volatile("ds_read_b128 %0, %1 offset:" STR2(OFF)                       \
               : "=v"(dst) : "v"(base))

__device__ inline float wave_sum(float v) {
#pragma unroll
  for (int off = 32; off; off >>= 1) v += __shfl_xor(v, off);
  return v;
}

__device__ inline void load_lds16(const bf16* g, bf16* l) {
  __builtin_amdgcn_global_load_lds((const __attribute__((address_space(1))) void*)g,
                                   (__attribute__((address_space(3))) void*)l, 16, 0, 0);
}

__device__ inline short bfbits(float f) {
  bf16 h = __float2bfloat16(f);
  return *(short*)&h;
}

// ---------------- weight cast + transpose
__global__ __launch_bounds__(256) void cast_transpose(const float* __restrict__ in,
                                                      bf16* __restrict__ out, int K, int N) {
  int e = blockIdx.x * 256 + threadIdx.x;
  if (e >= K * N) return;
  int n = e / K, k = e - n * K;
  out[e] = __float2bfloat16(in[k * N + n]);
}

// ---------------- zero the 15 pad rows of every (w, which, h) QKV block
__global__ __launch_bounds__(256) void zero_pads(bf16* __restrict__ qkv) {
  int idx = blockIdx.x * 256 + threadIdx.x;
  const int total = NWIN * 3 * NH * 15 * HD;
  if (idx >= total) return;
  int d = idx & 31; int rest = idx >> 5;
  int n = 49 + (rest % 15); rest /= 15;
  int h = rest % NH; rest /= NH;
  int which = rest % 3; int w = rest / 3;
  size_t base = (size_t)w * WBLK + (size_t)which * NH * HBLK + (size_t)h * HBLK;
  size_t addr = (which == 2) ? base + (size_t)d * NPAD + n : base + (size_t)n * HD + d;
  qkv[addr] = __float2bfloat16(0.0f);
}

// ---------------- bias+mask table: tbl[cls][h][row][64]
__global__ __launch_bounds__(256) void build_bias(const float* __restrict__ rel,
                                                  float* __restrict__ tbl) {
  int e = blockIdx.x * 256 + threadIdx.x;
  if (e >= 4 * 12 * 49 * 64) return;
  int col = e & 63; int t = e >> 6;
  int row = t % 49; t /= 49;
  int h = t % 12; int cls = t / 12;
  float v;
  if (col >= 49) {
    v = -1e30f;
  } else {
    int py = row / 7, px = row - py * 7;
    int qy = col / 7, qx = col - qy * 7;
    int ridx = (py - qy + 6) * 13 + (px - qx + 6);
    v = rel[ridx * 12 + h];
    int wy7 = cls >> 1, wx7 = cls & 1;
    int ly_r = wy7 ? (py < 4 ? 1 : 2) : 0;
    int lx_r = wx7 ? (px < 4 ? 1 : 2) : 0;
    int ly_c = wy7 ? (qy < 4 ? 1 : 2) : 0;
    int lx_c = wx7 ? (qx < 4 ? 1 : 2) : 0;
    if ((ly_r * 3 + lx_r) != (ly_c * 3 + lx_c)) v += -100.0f;
  }
  tbl[e] = v;
}

// ---------------- LayerNorm
template <int MODE>
__global__ __launch_bounds__(256) void ln_kernel(const float* __restrict__ x,
                                                 const float* __restrict__ g,
                                                 const float* __restrict__ be,
                                                 bf16* __restrict__ out) {
  int wv = threadIdx.x >> 6, lane = threadIdx.x & 63;
  int t = blockIdx.x * 4 + wv;
  size_t src;
  if (MODE == 0) {
    int w = t / 49, n = t - w * 49;
    int b = w >> 6, wi = w & 63;
    int wy = wi >> 3, wx = wi & 7;
    int py = n / 7, px = n - py * 7;
    int rr = wy * 7 + py, cc = wx * 7 + px;
    int ro = rr + 3; if (ro >= 56) ro -= 56;
    int co = cc + 3; if (co >= 56) co -= 56;
    src = (size_t)b * 3136 + ro * 56 + co;
  } else {
    src = (size_t)t;
  }
  const float2* row2 = (const float2*)(x + src * 384);
  float2 v[3]; float s = 0.f;
#pragma unroll
  for (int j = 0; j < 3; ++j) { v[j] = row2[lane + 64 * j]; s += v[j].x + v[j].y; }
  s = wave_sum(s);
  float mu = s * (1.f / 384.f);
  float q = 0.f;
#pragma unroll
  for (int j = 0; j < 3; ++j) {
    float dx = v[j].x - mu, dy = v[j].y - mu;
    q += dx * dx + dy * dy;
  }
  q = wave_sum(q);
  float rs = rsqrtf(q * (1.f / 384.f) + 1e-5f);
  uint* o = (uint*)(out + (size_t)t * 384);
  const float2* g2 = (const float2*)g;
  const float2* b2 = (const float2*)be;
#pragma unroll
  for (int j = 0; j < 3; ++j) {
    int c2 = lane + 64 * j;
    float2 gg = g2[c2], bb = b2[c2];
    float ox = (v[j].x - mu) * rs * gg.x + bb.x;
    float oy = (v[j].y - mu) * rs * gg.y + bb.y;
    o[c2] = (uint)(unsigned short)bfbits(ox) | ((uint)(unsigned short)bfbits(oy) << 16);
  }
}

// ---------------- PERSISTENT GEMM for K=384: C = A(M x 384) * B^T. One block per
// (bcol, M-strip): B-tile 128x384 LDS-resident (loaded once, swizzled gran^(row&7));
// A flows through 3x16KB BK=32 ring pipelined CONTINUOUSLY across the strip's tiles
// (prologue paid once per strip, not per tile). 8 waves (4M x 2N), wave-tile 64x64.
// Per iter: 8 inline-asm ds_read_b128 -> 16 MFMA; counted vmcnt(2); 1 barrier/iter.
// As swizzle gran^(row&3) (64B rows). Swapped-operand MFMA (thread holds 4 consec C-cols).
// EPI: 0=QKV scatter, 1=proj+residual+reverse, 2=GELU->h1
template <int EPI>
__global__ __launch_bounds__(512, 1) void gemm_persist(const bf16* __restrict__ A,
                                                       const bf16* __restrict__ BT,
                                                       int MT, int T, int C, int row0,
                                                       const float* __restrict__ bias,
                                                       const float* __restrict__ extra,
                                                       void* __restrict__ outp) {
  const int K = 384;
  __shared__ __align__(16) bf16 Bres[128 * 384];   // 96 KB
  __shared__ __align__(16) bf16 As[3][256 * 32];   // 48 KB  (total 144 KB)
  int tid = threadIdx.x, lane = tid & 63, wv = tid >> 6;
  int wr = wv >> 1, wc = wv & 1;
  int lr = lane & 15, lg = lane >> 4;
  int bid = blockIdx.x;
  int bcol = bid / C, sid = bid - bcol * C;
  int t0 = sid * T;
  if (t0 >= MT) return;
  int nt = MT - t0; if (nt > T) nt = T;
  int total = nt * 12;

  // ---- B resident load (12 gloads/thread), LDS[r][g] = G[r][g^(r&7)] (16B granules)
  const bf16* Bb = BT + (size_t)bcol * 128 * K;
  {
    int gi0 = wv * 64 + lane;
#pragma unroll
    for (int c = 0; c < 12; ++c) {
      int gi = c * 512 + gi0;
      int r = gi / 48, g = gi - r * 48;
      load_lds16(Bb + (size_t)r * K + ((g ^ (r & 7)) << 3), &Bres[c * 4096 + wv * 512]);
    }
  }

  // ---- A staging: stage = 256x32 (16 KB); wave stages 32 rows (2 chunks of 16).
  // LDS[row][g] = G[row][g ^ (row&3)] (4 granules of 8 elems per 32-col row).
  int srow = lane >> 2;
  int scol8 = (((lane & 3) ^ (srow & 3)) << 3);

#define STAGEP(fs)                                                            \
  {                                                                           \
    int ts_ = (fs) / 12, sk_ = (fs) - ts_ * 12;                               \
    const bf16* ab_ = A + ((size_t)(t0 + ts_) * 256 + wv * 32 + srow) * K     \
                        + sk_ * 32 + scol8;                                   \
    bf16* ld_ = &As[(fs) % 3][wv * 1024];                                     \
    load_lds16(ab_, ld_);                                                     \
    load_lds16(ab_ + (size_t)16 * K, ld_ + 512);                              \
  }

  STAGEP(0);
  STAGEP(1);
  asm volatile("s_waitcnt vmcnt(2)" ::: "memory");   // B + stage0 done; stage1 flying
  __builtin_amdgcn_s_barrier();

  float4 bias4[4];
#pragma unroll
  for (int j = 0; j < 4; ++j)
    bias4[j] = *(const float4*)(bias + bcol * 128 + wc * 64 + j * 16 + lg * 4);

  f32x4 acc[4][4] = {};
  int koffA = ((lg ^ (lr & 3)) << 3);
  int t_cur = 0;

  for (int it = 0; it < total; ++it) {
    if (it + 2 < total) STAGEP(it + 2);
    int buf = it % 3;
    int kk = it - (it / 12) * 12;
    cv3* pA = (cv3*)&As[buf][(wr * 64 + lr) * 32 + koffA];
    int bg = (((kk * 4 + lg) ^ (lr & 7)) << 3);
    cv3* pB = (cv3*)&Bres[(wc * 64 + lr) * 384 + bg];
    bf16x8 a[4], b[4];
    DSR(a[0], pA, 0); DSR(a[1], pA, 1024); DSR(a[2], pA, 2048); DSR(a[3], pA, 3072);
    DSR(b[0], pB, 0); DSR(b[1], pB, 12288); DSR(b[2], pB, 24576); DSR(b[3], pB, 36864);
    asm volatile("s_waitcnt lgkmcnt(0)" ::: "memory");
    __builtin_amdgcn_sched_barrier(0);
    __builtin_amdgcn_s_setprio(1);
#pragma unroll
    for (int i = 0; i < 4; ++i)
#pragma unroll
      for (int j = 0; j < 4; ++j)
        acc[i][j] = __builtin_amdgcn_mfma_f32_16x16x32_bf16(b[j], a[i], acc[i][j], 0, 0, 0);
    __builtin_amdgcn_s_setprio(0);

    if (kk == 11) {
      // -------- epilogue for tile t_cur --------
#pragma unroll
      for (int i = 0; i < 4; ++i) {
        int lrow = (t0 + t_cur) * 256 + wr * 64 + i * 16 + lr;
        int grow = row0 + lrow;
        int w_ = 0, n_ = 0; size_t tok = 0;
        if (EPI == 0 || EPI == 1) {
          w_ = grow / 49; n_ = grow - w_ * 49;
          if (EPI == 1) {
            int b_ = w_ >> 6, wi = w_ & 63;
            int wy = wi >> 3, wx = wi & 7;
            int py = n_ / 7, px = n_ - py * 7;
            int r2 = wy * 7 + py, c2 = wx * 7 + px;
            int ro = r2 + 3; if (ro >= 56) ro -= 56;
            int co = c2 + 3; if (co >= 56) co -= 56;
            tok = (size_t)b_ * 3136 + ro * 56 + co;
          }
        }
#pragma unroll
        for (int j = 0; j < 4; ++j) {
          int col = bcol * 128 + wc * 64 + j * 16 + lg * 4;
          float v0 = acc[i][j][0] + bias4[j].x;
          float v1 = acc[i][j][1] + bias4[j].y;
          float v2 = acc[i][j][2] + bias4[j].z;
          float v3 = acc[i][j][3] + bias4[j].w;
          if (EPI == 0) {
            int which = (col >= 768) ? 2 : (col >= 384 ? 1 : 0);
            int cc = col - which * 384;
            int hh = cc >> 5, d0 = cc & 31;
            size_t base = (size_t)w_ * WBLK + (size_t)which * NH * HBLK + (size_t)hh * HBLK;
            if (which == 2) {
              bf16* vp = (bf16*)outp + base + (size_t)d0 * NPAD + n_;
              vp[0] = __float2bfloat16(v0);
              vp[NPAD] = __float2bfloat16(v1);
              vp[2 * NPAD] = __float2bfloat16(v2);
              vp[3 * NPAD] = __float2bfloat16(v3);
            } else {
              bf16x4 p = {bfbits(v0), bfbits(v1), bfbits(v2), bfbits(v3)};
              *(bf16x4*)((bf16*)outp + base + (size_t)n_ * HD + d0) = p;
            }
          } else if (EPI == 1) {
            size_t oidx = tok * 384 + col;
            float4 e = *(const float4*)(extra + oidx);
            float4 o = {v0 + e.x, v1 + e.y, v2 + e.z, v3 + e.w};
            *(float4*)((float*)outp + oidx) = o;
          } else {
            float g0 = 0.5f * v0 * (1.0f + erff(v0 * 0.70710678118654752f));
            float g1 = 0.5f * v1 * (1.0f + erff(v1 * 0.70710678118654752f));
            float g2 = 0.5f * v2 * (1.0f + erff(v2 * 0.70710678118654752f));
            float g3 = 0.5f * v3 * (1.0f + erff(v3 * 0.70710678118654752f));
            bf16x4 p = {bfbits(g0), bfbits(g1), bfbits(g2), bfbits(g3)};
            *(bf16x4*)((bf16*)outp + (size_t)lrow * 1536 + col) = p;
          }
        }
      }
      ++t_cur;
#pragma unroll
      for (int i = 0; i < 4; ++i)
#pragma unroll
        for (int j = 0; j < 4; ++j)
          acc[i][j] = (f32x4){0.f, 0.f, 0.f, 0.f};
    }

    if (it + 1 < total) {
      if (it + 2 < total)
        asm volatile("s_waitcnt vmcnt(2)" ::: "memory");
      else
        asm volatile("s_waitcnt vmcnt(0)" ::: "memory");
      __builtin_amdgcn_s_barrier();
    }
  }
#undef STAGEP
}

// ---------------- GEMM (R8 structure) for MLP2 (K=1536). Tile 256x128, 8 waves,
// BK=64, 3-stage ring, 2-deep prefetch, counted vmcnt(6), inline-asm ds_read_b128.
// EPI fixed: out = acc + b2 + x1 -> d_out
__global__ __launch_bounds__(512, 2) void gemm_mlp2(const bf16* __restrict__ A,
                                                    const bf16* __restrict__ BT,
                                                    int K, int NCOL, int row0,
                                                    const float* __restrict__ bias,
                                                    const float* __restrict__ extra,
                                                    void* __restrict__ outp) {
  __shared__ __align__(16) bf16 As[3][256 * 64];
  __shared__ __align__(16) bf16 Bs[3][128 * 64];
  int tid = threadIdx.x;
  int lane = tid & 63, wv = tid >> 6;
  int wr = wv >> 1, wc = wv & 1;
  int lr = lane & 15, lg = lane >> 4;

  int nwg = gridDim.x;
  int bid = blockIdx.x;
  int xcd = bid & 7, li = bid >> 3;
  int qq = nwg >> 3, rr8 = nwg & 7;
  int start = xcd * qq + (xcd < rr8 ? xcd : rr8);
  int lin = start + li;
  int brow = lin / NCOL, bcol = lin - brow * NCOL;

  const bf16* Ab = A + (size_t)brow * 256 * K;
  const bf16* Bb = BT + (size_t)bcol * 128 * K;

  int srow = lane >> 3;
  int scol = ((lane & 7) * 8) ^ (srow << 3);
  const bf16* aS = Ab + (size_t)(wv * 32 + srow) * K + scol;
  const bf16* bS = Bb + (size_t)(wv * 16 + srow) * K + scol;

  f32x4 acc[4][4] = {};
  int nk = K >> 6;
  int xorm = (lr & 7) << 3;

#define STAGE(buf)                                                        \
  {                                                                       \
    _Pragma("unroll") for (int c = 0; c < 4; ++c)                         \
        load_lds16(aS + (size_t)c * 8 * K, &As[buf][wv * 2048 + c * 512]);\
    _Pragma("unroll") for (int c = 0; c < 2; ++c)                         \
        load_lds16(bS + (size_t)c * 8 * K, &Bs[buf][wv * 1024 + c * 512]);\
    aS += 64; bS += 64;                                                   \
  }

  STAGE(0);
  STAGE(1);
  asm volatile("s_waitcnt vmcnt(6)" ::: "memory");
  __builtin_amdgcn_s_barrier();

  for (int kk = 0; kk < nk; ++kk) {
    int cur = kk % 3;
    if (kk + 2 < nk) STAGE((kk + 2) % 3);
    int k0 = (lg * 8) ^ xorm;
    int k1 = (32 + lg * 8) ^ xorm;
    cv3* pA0 = (cv3*)&As[cur][(wr * 64 + lr) * 64 + k0];
    cv3* pB0 = (cv3*)&Bs[cur][(wc * 64 + lr) * 64 + k0];
    cv3* pA1 = (cv3*)&As[cur][(wr * 64 + lr) * 64 + k1];
    cv3* pB1 = (cv3*)&Bs[cur][(wc * 64 + lr) * 64 + k1];
    bf16x8 a0[4], b0[4], a1[4], b1[4];
    DSR(a0[0], pA0, 0); DSR(a0[1], pA0, 2048); DSR(a0[2], pA0, 4096); DSR(a0[3], pA0, 6144);
    DSR(b0[0], pB0, 0); DSR(b0[1], pB0, 2048); DSR(b0[2], pB0, 4096); DSR(b0[3], pB0, 6144);
    asm volatile("s_waitcnt lgkmcnt(0)" ::: "memory");
    __builtin_amdgcn_sched_barrier(0);
    DSR(a1[0], pA1, 0); DSR(a1[1], pA1, 2048); DSR(a1[2], pA1, 4096); DSR(a1[3], pA1, 6144);
    DSR(b1[0], pB1, 0); DSR(b1[1], pB1, 2048); DSR(b1[2], pB1, 4096); DSR(b1[3], pB1, 6144);
    __builtin_amdgcn_sched_barrier(0);
#pragma unroll
    for (int i = 0; i < 4; ++i)
#pragma unroll
      for (int j = 0; j < 4; ++j)
        acc[i][j] = __builtin_amdgcn_mfma_f32_16x16x32_bf16(b0[j], a0[i], acc[i][j], 0, 0, 0);
    asm volatile("s_waitcnt lgkmcnt(0)" ::: "memory");
    __builtin_amdgcn_sched_barrier(0);
#pragma unroll
    for (int i = 0; i < 4; ++i)
#pragma unroll
      for (int j = 0; j < 4; ++j)
        acc[i][j] = __builtin_amdgcn_mfma_f32_16x16x32_bf16(b1[j], a1[i], acc[i][j], 0, 0, 0);
    if (kk + 1 < nk) {
      if (kk + 2 < nk)
        asm volatile("s_waitcnt vmcnt(6)" ::: "memory");
      else
        asm volatile("s_waitcnt vmcnt(0)" ::: "memory");
      __builtin_amdgcn_s_barrier();
    }
  }
#undef STAGE

  float4 bias4[4];
#pragma unroll
  for (int j = 0; j < 4; ++j)
    bias4[j] = *(const float4*)(bias + bcol * 128 + wc * 64 + j * 16 + lg * 4);

#pragma unroll
  for (int i = 0; i < 4; ++i) {
    int lrow = brow * 256 + wr * 64 + i * 16 + lr;
    int grow = row0 + lrow;
#pragma unroll
    for (int j = 0; j < 4; ++j) {
      int col = bcol * 128 + wc * 64 + j * 16 + lg * 4;
      size_t oidx = (size_t)grow * 384 + col;
      float4 e = *(const float4*)(extra + oidx);
      float4 o = {acc[i][j][0] + bias4[j].x + e.x, acc[i][j][1] + bias4[j].y + e.y,
                  acc[i][j][2] + bias4[j].z + e.z, acc[i][j][3] + bias4[j].w + e.w};
      *(float4*)((float*)outp + oidx) = o;
    }
  }
}

// ---------------- windowed attention (R8): 1 block per window, 4 waves x 3 heads.
__global__ __launch_bounds__(256) void attn_kernel(const bf16* __restrict__ qkv,
                                                   const float* __restrict__ tbl,
                                                   bf16* __restrict__ attn_out) {
  __shared__ __align__(16) bf16 P[4][64 * 72];
  int wv = threadIdx.x >> 6, lane = threadIdx.x & 63;
  int lr = lane & 15, lg = lane >> 4;
  int w = blockIdx.x;
  int wi = w & 63, wy = wi >> 3, wx = wi & 7;
  int cls = ((wy == 7) ? 2 : 0) | ((wx == 7) ? 1 : 0);
  const bf16* base = qkv + (size_t)w * WBLK;
  bf16* Pl = &P[wv][0];
  const float scale = 0.17677669529663689f;

  for (int hh = 0; hh < 3; ++hh) {
    int h = wv + hh * 4;
    const bf16* Q  = base + (size_t)h * HBLK;
    const bf16* Kp = base + (size_t)(NH + h) * HBLK;
    const bf16* Vt = base + (size_t)(2 * NH + h) * HBLK;
    const float* tb = tbl + (size_t)(cls * 12 + h) * 49 * 64;

    bf16x8 qa[4], kb[4];
#pragma unroll
    for (int t = 0; t < 4; ++t) {
      qa[t] = *(const bf16x8*)(Q  + (t * 16 + lr) * 32 + lg * 8);
      kb[t] = *(const bf16x8*)(Kp + (t * 16 + lr) * 32 + lg * 8);
    }
    f32x4 S[4][4] = {};
#pragma unroll
    for (int i = 0; i < 4; ++i)
#pragma unroll
      for (int j = 0; j < 4; ++j)
        S[i][j] = __builtin_amdgcn_mfma_f32_16x16x32_bf16(qa[i], kb[j], S[i][j], 0, 0, 0);

#pragma unroll
    for (int i = 0; i < 4; ++i) {
#pragma unroll
      for (int r = 0; r < 4; ++r) {
        int row = i * 16 + lg * 4 + r;
        const float* trow = tb + (row < 49 ? row : 0) * 64;
        float sv[4]; float m = -1e30f;
#pragma unroll
        for (int j = 0; j < 4; ++j) {
          float s = S[i][j][r] * scale + trow[j * 16 + lr];
          sv[j] = s;
          m = fmaxf(m, s);
        }
        m = fmaxf(m, __shfl_xor(m, 1));
        m = fmaxf(m, __shfl_xor(m, 2));
        m = fmaxf(m, __shfl_xor(m, 4));
        m = fmaxf(m, __shfl_xor(m, 8));
        float ev[4]; float sum = 0.f;
#pragma unroll
        for (int j = 0; j < 4; ++j) { ev[j] = __expf(sv[j] - m); sum += ev[j]; }
        sum += __shfl_xor(sum, 1);
        sum += __shfl_xor(sum, 2);
        sum += __shfl_xor(sum, 4);
        sum += __shfl_xor(sum, 8);
        float inv = 1.0f / sum;
#pragma unroll
        for (int j = 0; j < 4; ++j)
          Pl[row * 72 + j * 16 + lr] = __float2bfloat16(ev[j] * inv);
      }
    }

    bf16x8 vb[2][2];
#pragma unroll
    for (int kt = 0; kt < 2; ++kt)
#pragma unroll
      for (int cj = 0; cj < 2; ++cj)
        vb[kt][cj] = *(const bf16x8*)(Vt + (cj * 16 + lr) * 64 + kt * 32 + lg * 8);
    f32x4 O[4][2] = {};
#pragma unroll
    for (int i = 0; i < 4; ++i) {
#pragma unroll
      for (int kt = 0; kt < 2; ++kt) {
        bf16x8 pa = *(const bf16x8*)(Pl + (i * 16 + lr) * 72 + kt * 32 + lg * 8);
#pragma unroll
        for (int cj = 0; cj < 2; ++cj)
          O[i][cj] = __builtin_amdgcn_mfma_f32_16x16x32_bf16(pa, vb[kt][cj], O[i][cj], 0, 0, 0);
      }
    }
#pragma unroll
    for (int i = 0; i < 4; ++i)
#pragma unroll
      for (int cj = 0; cj < 2; ++cj)
#pragma unroll
        for (int r = 0; r < 4; ++r) {
          int n = i * 16 + lg * 4 + r;
          if (n < 49)
            attn_out[((size_t)w * 49 + n) * 384 + h * 32 + cj * 16 + lr] =
                __float2bfloat16(O[i][cj][r]);
        }
  }
}

extern "C" void kernel_launch(void* const* d_in, const int* in_sizes, int n_in,
                              void* d_out, int out_size, void* d_ws, size_t ws_size,
                              hipStream_t stream) {
  (void)in_sizes; (void)n_in; (void)out_size;
  const float* x     = (const float*)d_in[0];
  const float* g1    = (const float*)d_in[1];
  const float* be1   = (const float*)d_in[2];
  const float* w_qkv = (const float*)d_in[3];
  const float* b_qkv = (const float*)d_in[4];
  const float* rel   = (const float*)d_in[5];
  const float* w_pr  = (const float*)d_in[6];
  const float* b_pr  = (const float*)d_in[7];
  const float* g2    = (const float*)d_in[8];
  const float* be2   = (const float*)d_in[9];
  const float* w1    = (const float*)d_in[10];
  const float* b1    = (const float*)d_in[11];
  const float* w2    = (const float*)d_in[12];
  const float* b2    = (const float*)d_in[13];
  float* out = (float*)d_out;

  if (ws_size < 390070272u) return;

  char* ws = (char*)d_ws;
  bf16* wqkvT = (bf16*)(ws);                     // 1152 x 384
  bf16* wprT  = (bf16*)(ws + 884736);            // 384 x 384
  bf16* w1T   = (bf16*)(ws + 1179648);           // 1536 x 384
  bf16* w2T   = (bf16*)(ws + 2359296);           // 384 x 1536
  float* btbl = (float*)(ws + 3538944);          // 4 x 12 x 49 x 64 f32
  bf16* xw    = (bf16*)(ws + (4u << 20));        // 100352 x 384 bf16
  bf16* qkv   = (bf16*)(ws + (84u << 20));       // padded QKV (302 MB; reused)
  bf16* m_in  = qkv;                             // LN2 out (77 MB) reuses qkv head
  bf16* h1    = (bf16*)(ws + (164u << 20));      // 50176 x 1536 bf16 chunk

  cast_transpose<<<dim3((442368 + 255) / 256), 256, 0, stream>>>(w_qkv, wqkvT, 384, 1152);
  cast_transpose<<<dim3((147456 + 255) / 256), 256, 0, stream>>>(w_pr, wprT, 384, 384);
  cast_transpose<<<dim3((589824 + 255) / 256), 256, 0, stream>>>(w1, w1T, 384, 1536);
  cast_transpose<<<dim3((589824 + 255) / 256), 256, 0, stream>>>(w2, w2T, 1536, 384);

  build_bias<<<dim3((4 * 12 * 49 * 64 + 255) / 256), 256, 0, stream>>>(rel, btbl);

  zero_pads<<<dim3((NWIN * 3 * NH * 15 * HD + 255) / 256), 256, 0, stream>>>(qkv);

  ln_kernel<0><<<dim3(NTOK / 4), 256, 0, stream>>>(x, g1, be1, xw);

  // QKV: 9 bcols x 28 strips (strip = 14 tiles of 256 rows, 392 total)
  gemm_persist<0><<<dim3(252), 512, 0, stream>>>(xw, wqkvT, 392, 14, 28, 0,
                                                 b_qkv, nullptr, (void*)qkv);

  attn_kernel<<<dim3(NWIN), 256, 0, stream>>>(qkv, btbl, xw);

  // proj: 3 bcols x 84 strips (strip = 5 tiles, ragged)
  gemm_persist<1><<<dim3(252), 512, 0, stream>>>(xw, wprT, 392, 5, 84, 0,
                                                 b_pr, x, (void*)out);

  ln_kernel<1><<<dim3(NTOK / 4), 256, 0, stream>>>(out, g2, be2, m_in);

  for (int c = 0; c < 2; ++c) {
    // MLP1: 12 bcols x 21 strips (strip = 10 tiles over 196, ragged)
    gemm_persist<2><<<dim3(252), 512, 0, stream>>>(m_in + (size_t)c * 50176 * 384, w1T,
                                                   196, 10, 21, c * 50176,
                                                   b1, nullptr, (void*)h1);
    // MLP2: R8 structure (K=1536), 196 x 3 = 588
    gemm_mlp2<<<dim3(588), 512, 0, stream>>>(h1, w2T, 1536, 3, c * 50176, b2, out,
                                             (void*)out);
  }
}

// Round 13
// 983.359 us; speedup vs baseline: 1.0584x; 1.0059x over previous
//
#include <hip/hip_runtime.h>
#include <hip/hip_bf16.h>
#include <math.h>

typedef __attribute__((ext_vector_type(8))) short bf16x8;
typedef __attribute__((ext_vector_type(4))) short bf16x4;
typedef __attribute__((ext_vector_type(4))) float f32x4;
typedef __hip_bfloat16 bf16;

#define NH 12
#define HD 32
#define NPAD 64
#define NWIN 2048
#define NTOK 100352
#define HBLK (NPAD*HD)
#define WBLK (3*NH*HBLK)

typedef __attribute__((address_space(3))) const void cv3;

#define STR2(x) #x
#define DSR(dst, base, OFF)                                                  \
  asm volatile("ds_read_b128 %0, %1 offset:" STR2(OFF)                       \
               : "=v"(dst) : "v"(base))

__device__ inline float wave_sum(float v) {
#pragma unroll
  for (int off = 32; off; off >>= 1) v += __shfl_xor(v, off);
  return v;
}

__device__ inline void load_lds16(const bf16* g, bf16* l) {
  __builtin_amdgcn_global_load_lds((const __attribute__((address_space(1))) void*)g,
                                   (__attribute__((address_space(3))) void*)l, 16, 0, 0);
}

__device__ inline short bfbits(float f) {
  bf16 h = __float2bfloat16(f);
  return *(short*)&h;
}

// ---------------- weight cast + transpose
__global__ __launch_bounds__(256) void cast_transpose(const float* __restrict__ in,
                                                      bf16* __restrict__ out, int K, int N) {
  int e = blockIdx.x * 256 + threadIdx.x;
  if (e >= K * N) return;
  int n = e / K, k = e - n * K;
  out[e] = __float2bfloat16(in[k * N + n]);
}

// ---------------- zero the 15 pad rows of every (w, which, h) QKV block
__global__ __launch_bounds__(256) void zero_pads(bf16* __restrict__ qkv) {
  int idx = blockIdx.x * 256 + threadIdx.x;
  const int total = NWIN * 3 * NH * 15 * HD;
  if (idx >= total) return;
  int d = idx & 31; int rest = idx >> 5;
  int n = 49 + (rest % 15); rest /= 15;
  int h = rest % NH; rest /= NH;
  int which = rest % 3; int w = rest / 3;
  size_t base = (size_t)w * WBLK + (size_t)which * NH * HBLK + (size_t)h * HBLK;
  size_t addr = (which == 2) ? base + (size_t)d * NPAD + n : base + (size_t)n * HD + d;
  qkv[addr] = __float2bfloat16(0.0f);
}

// ---------------- bias+mask table: tbl[cls][h][row][64]
__global__ __launch_bounds__(256) void build_bias(const float* __restrict__ rel,
                                                  float* __restrict__ tbl) {
  int e = blockIdx.x * 256 + threadIdx.x;
  if (e >= 4 * 12 * 49 * 64) return;
  int col = e & 63; int t = e >> 6;
  int row = t % 49; t /= 49;
  int h = t % 12; int cls = t / 12;
  float v;
  if (col >= 49) {
    v = -1e30f;
  } else {
    int py = row / 7, px = row - py * 7;
    int qy = col / 7, qx = col - qy * 7;
    int ridx = (py - qy + 6) * 13 + (px - qx + 6);
    v = rel[ridx * 12 + h];
    int wy7 = cls >> 1, wx7 = cls & 1;
    int ly_r = wy7 ? (py < 4 ? 1 : 2) : 0;
    int lx_r = wx7 ? (px < 4 ? 1 : 2) : 0;
    int ly_c = wy7 ? (qy < 4 ? 1 : 2) : 0;
    int lx_c = wx7 ? (qx < 4 ? 1 : 2) : 0;
    if ((ly_r * 3 + lx_r) != (ly_c * 3 + lx_c)) v += -100.0f;
  }
  tbl[e] = v;
}

// ---------------- LayerNorm
template <int MODE>
__global__ __launch_bounds__(256) void ln_kernel(const float* __restrict__ x,
                                                 const float* __restrict__ g,
                                                 const float* __restrict__ be,
                                                 bf16* __restrict__ out) {
  int wv = threadIdx.x >> 6, lane = threadIdx.x & 63;
  int t = blockIdx.x * 4 + wv;
  size_t src;
  if (MODE == 0) {
    int w = t / 49, n = t - w * 49;
    int b = w >> 6, wi = w & 63;
    int wy = wi >> 3, wx = wi & 7;
    int py = n / 7, px = n - py * 7;
    int rr = wy * 7 + py, cc = wx * 7 + px;
    int ro = rr + 3; if (ro >= 56) ro -= 56;
    int co = cc + 3; if (co >= 56) co -= 56;
    src = (size_t)b * 3136 + ro * 56 + co;
  } else {
    src = (size_t)t;
  }
  const float2* row2 = (const float2*)(x + src * 384);
  float2 v[3]; float s = 0.f;
#pragma unroll
  for (int j = 0; j < 3; ++j) { v[j] = row2[lane + 64 * j]; s += v[j].x + v[j].y; }
  s = wave_sum(s);
  float mu = s * (1.f / 384.f);
  float q = 0.f;
#pragma unroll
  for (int j = 0; j < 3; ++j) {
    float dx = v[j].x - mu, dy = v[j].y - mu;
    q += dx * dx + dy * dy;
  }
  q = wave_sum(q);
  float rs = rsqrtf(q * (1.f / 384.f) + 1e-5f);
  uint* o = (uint*)(out + (size_t)t * 384);
  const float2* g2 = (const float2*)g;
  const float2* b2 = (const float2*)be;
#pragma unroll
  for (int j = 0; j < 3; ++j) {
    int c2 = lane + 64 * j;
    float2 gg = g2[c2], bb = b2[c2];
    float ox = (v[j].x - mu) * rs * gg.x + bb.x;
    float oy = (v[j].y - mu) * rs * gg.y + bb.y;
    o[c2] = (uint)(unsigned short)bfbits(ox) | ((uint)(unsigned short)bfbits(oy) << 16);
  }
}

// ---------------- PERSISTENT GEMM for K=384 (R12 structure, swizzle FIXED + split lgkm).
// One block per (bcol, M-strip): B-tile 128x384 LDS-resident; A flows through 3x16KB
// BK=32 ring pipelined across tiles. 8 waves (4M x 2N), wave-tile 64x64.
// A-swizzle (64B rows): LDS[row][s] = G[row][s ^ ((row>>1)&3)] in 16B granules ->
// quarter-wave slot = 4*(lr&1) + (lg^((lr>>1)&3)) covers all 8 slots, 2 lanes each (free).
// Per iter: a0,b0-3,a1-3 reads; lgkm(3) -> 4 MFMA; lgkm(0) -> 12 MFMA; vmcnt(2); barrier.
// EPI: 0=QKV scatter, 1=proj+residual+reverse, 2=GELU->h1
template <int EPI>
__global__ __launch_bounds__(512, 1) void gemm_persist(const bf16* __restrict__ A,
                                                       const bf16* __restrict__ BT,
                                                       int MT, int T, int C, int row0,
                                                       const float* __restrict__ bias,
                                                       const float* __restrict__ extra,
                                                       void* __restrict__ outp) {
  const int K = 384;
  __shared__ __align__(16) bf16 Bres[128 * 384];   // 96 KB
  __shared__ __align__(16) bf16 As[3][256 * 32];   // 48 KB  (total 144 KB)
  int tid = threadIdx.x, lane = tid & 63, wv = tid >> 6;
  int wr = wv >> 1, wc = wv & 1;
  int lr = lane & 15, lg = lane >> 4;
  int bid = blockIdx.x;
  int bcol = bid / C, sid = bid - bcol * C;
  int t0 = sid * T;
  if (t0 >= MT) return;
  int nt = MT - t0; if (nt > T) nt = T;
  int total = nt * 12;

  // ---- B resident load, LDS[r][g] = G[r][g^(r&7)] (16B granules, 768B rows: free)
  const bf16* Bb = BT + (size_t)bcol * 128 * K;
  {
    int gi0 = wv * 64 + lane;
#pragma unroll
    for (int c = 0; c < 12; ++c) {
      int gi = c * 512 + gi0;
      int r = gi / 48, g = gi - r * 48;
      load_lds16(Bb + (size_t)r * K + ((g ^ (r & 7)) << 3), &Bres[c * 4096 + wv * 512]);
    }
  }

  // ---- A staging: stage = 256x32 (16 KB); wave stages 32 rows (2 chunks of 16).
  // FIXED swizzle: source granule = (lane&3) ^ ((srow>>1)&3).
  int srow = lane >> 2;
  int scol8 = (((lane & 3) ^ ((srow >> 1) & 3)) << 3);

#define STAGEP(fs)                                                            \
  {                                                                           \
    int ts_ = (fs) / 12, sk_ = (fs) - ts_ * 12;                               \
    const bf16* ab_ = A + ((size_t)(t0 + ts_) * 256 + wv * 32 + srow) * K     \
                        + sk_ * 32 + scol8;                                   \
    bf16* ld_ = &As[(fs) % 3][wv * 1024];                                     \
    load_lds16(ab_, ld_);                                                     \
    load_lds16(ab_ + (size_t)16 * K, ld_ + 512);                              \
  }

  STAGEP(0);
  STAGEP(1);
  asm volatile("s_waitcnt vmcnt(2)" ::: "memory");   // B + stage0 done; stage1 flying
  __builtin_amdgcn_s_barrier();

  float4 bias4[4];
#pragma unroll
  for (int j = 0; j < 4; ++j)
    bias4[j] = *(const float4*)(bias + bcol * 128 + wc * 64 + j * 16 + lg * 4);

  f32x4 acc[4][4] = {};
  int koffA = ((lg ^ ((lr >> 1) & 3)) << 3);         // FIXED read swizzle
  int t_cur = 0;

  for (int it = 0; it < total; ++it) {
    if (it + 2 < total) STAGEP(it + 2);
    int buf = it % 3;
    int kk = it - (it / 12) * 12;
    cv3* pA = (cv3*)&As[buf][(wr * 64 + lr) * 32 + koffA];
    int bg = (((kk * 4 + lg) ^ (lr & 7)) << 3);
    cv3* pB = (cv3*)&Bres[(wc * 64 + lr) * 384 + bg];
    bf16x8 a[4], b[4];
    // order: a0 + all b first (first MFMA cluster's deps), then a1-a3
    DSR(a[0], pA, 0);
    DSR(b[0], pB, 0); DSR(b[1], pB, 12288); DSR(b[2], pB, 24576); DSR(b[3], pB, 36864);
    DSR(a[1], pA, 1024); DSR(a[2], pA, 2048); DSR(a[3], pA, 3072);
    asm volatile("s_waitcnt lgkmcnt(3)" ::: "memory");   // a0,b0..b3 done; a1-3 flying
    __builtin_amdgcn_sched_barrier(0);
    __builtin_amdgcn_s_setprio(1);
#pragma unroll
    for (int j = 0; j < 4; ++j)
      acc[0][j] = __builtin_amdgcn_mfma_f32_16x16x32_bf16(b[j], a[0], acc[0][j], 0, 0, 0);
    __builtin_amdgcn_s_setprio(0);
    asm volatile("s_waitcnt lgkmcnt(0)" ::: "memory");
    __builtin_amdgcn_sched_barrier(0);
    __builtin_amdgcn_s_setprio(1);
#pragma unroll
    for (int i = 1; i < 4; ++i)
#pragma unroll
      for (int j = 0; j < 4; ++j)
        acc[i][j] = __builtin_amdgcn_mfma_f32_16x16x32_bf16(b[j], a[i], acc[i][j], 0, 0, 0);
    __builtin_amdgcn_s_setprio(0);

    if (kk == 11) {
      // -------- epilogue for tile t_cur --------
#pragma unroll
      for (int i = 0; i < 4; ++i) {
        int lrow = (t0 + t_cur) * 256 + wr * 64 + i * 16 + lr;
        int grow = row0 + lrow;
        int w_ = 0, n_ = 0; size_t tok = 0;
        if (EPI == 0 || EPI == 1) {
          w_ = grow / 49; n_ = grow - w_ * 49;
          if (EPI == 1) {
            int b_ = w_ >> 6, wi = w_ & 63;
            int wy = wi >> 3, wx = wi & 7;
            int py = n_ / 7, px = n_ - py * 7;
            int r2 = wy * 7 + py, c2 = wx * 7 + px;
            int ro = r2 + 3; if (ro >= 56) ro -= 56;
            int co = c2 + 3; if (co >= 56) co -= 56;
            tok = (size_t)b_ * 3136 + ro * 56 + co;
          }
        }
#pragma unroll
        for (int j = 0; j < 4; ++j) {
          int col = bcol * 128 + wc * 64 + j * 16 + lg * 4;
          float v0 = acc[i][j][0] + bias4[j].x;
          float v1 = acc[i][j][1] + bias4[j].y;
          float v2 = acc[i][j][2] + bias4[j].z;
          float v3 = acc[i][j][3] + bias4[j].w;
          if (EPI == 0) {
            int which = (col >= 768) ? 2 : (col >= 384 ? 1 : 0);
            int cc = col - which * 384;
            int hh = cc >> 5, d0 = cc & 31;
            size_t base = (size_t)w_ * WBLK + (size_t)which * NH * HBLK + (size_t)hh * HBLK;
            if (which == 2) {
              bf16* vp = (bf16*)outp + base + (size_t)d0 * NPAD + n_;
              vp[0] = __float2bfloat16(v0);
              vp[NPAD] = __float2bfloat16(v1);
              vp[2 * NPAD] = __float2bfloat16(v2);
              vp[3 * NPAD] = __float2bfloat16(v3);
            } else {
              bf16x4 p = {bfbits(v0), bfbits(v1), bfbits(v2), bfbits(v3)};
              *(bf16x4*)((bf16*)outp + base + (size_t)n_ * HD + d0) = p;
            }
          } else if (EPI == 1) {
            size_t oidx = tok * 384 + col;
            float4 e = *(const float4*)(extra + oidx);
            float4 o = {v0 + e.x, v1 + e.y, v2 + e.z, v3 + e.w};
            *(float4*)((float*)outp + oidx) = o;
          } else {
            float g0 = 0.5f * v0 * (1.0f + erff(v0 * 0.70710678118654752f));
            float g1 = 0.5f * v1 * (1.0f + erff(v1 * 0.70710678118654752f));
            float g2 = 0.5f * v2 * (1.0f + erff(v2 * 0.70710678118654752f));
            float g3 = 0.5f * v3 * (1.0f + erff(v3 * 0.70710678118654752f));
            bf16x4 p = {bfbits(g0), bfbits(g1), bfbits(g2), bfbits(g3)};
            *(bf16x4*)((bf16*)outp + (size_t)lrow * 1536 + col) = p;
          }
        }
      }
      ++t_cur;
#pragma unroll
      for (int i = 0; i < 4; ++i)
#pragma unroll
        for (int j = 0; j < 4; ++j)
          acc[i][j] = (f32x4){0.f, 0.f, 0.f, 0.f};
    }

    if (it + 1 < total) {
      if (it + 2 < total)
        asm volatile("s_waitcnt vmcnt(2)" ::: "memory");
      else
        asm volatile("s_waitcnt vmcnt(0)" ::: "memory");
      __builtin_amdgcn_s_barrier();
    }
  }
#undef STAGEP
}

// ---------------- GEMM (R8 structure) for MLP2 (K=1536).
__global__ __launch_bounds__(512, 2) void gemm_mlp2(const bf16* __restrict__ A,
                                                    const bf16* __restrict__ BT,
                                                    int K, int NCOL, int row0,
                                                    const float* __restrict__ bias,
                                                    const float* __restrict__ extra,
                                                    void* __restrict__ outp) {
  __shared__ __align__(16) bf16 As[3][256 * 64];
  __shared__ __align__(16) bf16 Bs[3][128 * 64];
  int tid = threadIdx.x;
  int lane = tid & 63, wv = tid >> 6;
  int wr = wv >> 1, wc = wv & 1;
  int lr = lane & 15, lg = lane >> 4;

  int nwg = gridDim.x;
  int bid = blockIdx.x;
  int xcd = bid & 7, li = bid >> 3;
  int qq = nwg >> 3, rr8 = nwg & 7;
  int start = xcd * qq + (xcd < rr8 ? xcd : rr8);
  int lin = start + li;
  int brow = lin / NCOL, bcol = lin - brow * NCOL;

  const bf16* Ab = A + (size_t)brow * 256 * K;
  const bf16* Bb = BT + (size_t)bcol * 128 * K;

  int srow = lane >> 3;
  int scol = ((lane & 7) * 8) ^ (srow << 3);
  const bf16* aS = Ab + (size_t)(wv * 32 + srow) * K + scol;
  const bf16* bS = Bb + (size_t)(wv * 16 + srow) * K + scol;

  f32x4 acc[4][4] = {};
  int nk = K >> 6;
  int xorm = (lr & 7) << 3;

#define STAGE(buf)                                                        \
  {                                                                       \
    _Pragma("unroll") for (int c = 0; c < 4; ++c)                         \
        load_lds16(aS + (size_t)c * 8 * K, &As[buf][wv * 2048 + c * 512]);\
    _Pragma("unroll") for (int c = 0; c < 2; ++c)                         \
        load_lds16(bS + (size_t)c * 8 * K, &Bs[buf][wv * 1024 + c * 512]);\
    aS += 64; bS += 64;                                                   \
  }

  STAGE(0);
  STAGE(1);
  asm volatile("s_waitcnt vmcnt(6)" ::: "memory");
  __builtin_amdgcn_s_barrier();

  for (int kk = 0; kk < nk; ++kk) {
    int cur = kk % 3;
    if (kk + 2 < nk) STAGE((kk + 2) % 3);
    int k0 = (lg * 8) ^ xorm;
    int k1 = (32 + lg * 8) ^ xorm;
    cv3* pA0 = (cv3*)&As[cur][(wr * 64 + lr) * 64 + k0];
    cv3* pB0 = (cv3*)&Bs[cur][(wc * 64 + lr) * 64 + k0];
    cv3* pA1 = (cv3*)&As[cur][(wr * 64 + lr) * 64 + k1];
    cv3* pB1 = (cv3*)&Bs[cur][(wc * 64 + lr) * 64 + k1];
    bf16x8 a0[4], b0[4], a1[4], b1[4];
    DSR(a0[0], pA0, 0); DSR(a0[1], pA0, 2048); DSR(a0[2], pA0, 4096); DSR(a0[3], pA0, 6144);
    DSR(b0[0], pB0, 0); DSR(b0[1], pB0, 2048); DSR(b0[2], pB0, 4096); DSR(b0[3], pB0, 6144);
    asm volatile("s_waitcnt lgkmcnt(0)" ::: "memory");
    __builtin_amdgcn_sched_barrier(0);
    DSR(a1[0], pA1, 0); DSR(a1[1], pA1, 2048); DSR(a1[2], pA1, 4096); DSR(a1[3], pA1, 6144);
    DSR(b1[0], pB1, 0); DSR(b1[1], pB1, 2048); DSR(b1[2], pB1, 4096); DSR(b1[3], pB1, 6144);
    __builtin_amdgcn_sched_barrier(0);
#pragma unroll
    for (int i = 0; i < 4; ++i)
#pragma unroll
      for (int j = 0; j < 4; ++j)
        acc[i][j] = __builtin_amdgcn_mfma_f32_16x16x32_bf16(b0[j], a0[i], acc[i][j], 0, 0, 0);
    asm volatile("s_waitcnt lgkmcnt(0)" ::: "memory");
    __builtin_amdgcn_sched_barrier(0);
#pragma unroll
    for (int i = 0; i < 4; ++i)
#pragma unroll
      for (int j = 0; j < 4; ++j)
        acc[i][j] = __builtin_amdgcn_mfma_f32_16x16x32_bf16(b1[j], a1[i], acc[i][j], 0, 0, 0);
    if (kk + 1 < nk) {
      if (kk + 2 < nk)
        asm volatile("s_waitcnt vmcnt(6)" ::: "memory");
      else
        asm volatile("s_waitcnt vmcnt(0)" ::: "memory");
      __builtin_amdgcn_s_barrier();
    }
  }
#undef STAGE

  float4 bias4[4];
#pragma unroll
  for (int j = 0; j < 4; ++j)
    bias4[j] = *(const float4*)(bias + bcol * 128 + wc * 64 + j * 16 + lg * 4);

#pragma unroll
  for (int i = 0; i < 4; ++i) {
    int lrow = brow * 256 + wr * 64 + i * 16 + lr;
    int grow = row0 + lrow;
#pragma unroll
    for (int j = 0; j < 4; ++j) {
      int col = bcol * 128 + wc * 64 + j * 16 + lg * 4;
      size_t oidx = (size_t)grow * 384 + col;
      float4 e = *(const float4*)(extra + oidx);
      float4 o = {acc[i][j][0] + bias4[j].x + e.x, acc[i][j][1] + bias4[j].y + e.y,
                  acc[i][j][2] + bias4[j].z + e.z, acc[i][j][3] + bias4[j].w + e.w};
      *(float4*)((float*)outp + oidx) = o;
    }
  }
}

// ---------------- windowed attention (R8): 1 block per window, 4 waves x 3 heads.
__global__ __launch_bounds__(256) void attn_kernel(const bf16* __restrict__ qkv,
                                                   const float* __restrict__ tbl,
                                                   bf16* __restrict__ attn_out) {
  __shared__ __align__(16) bf16 P[4][64 * 72];
  int wv = threadIdx.x >> 6, lane = threadIdx.x & 63;
  int lr = lane & 15, lg = lane >> 4;
  int w = blockIdx.x;
  int wi = w & 63, wy = wi >> 3, wx = wi & 7;
  int cls = ((wy == 7) ? 2 : 0) | ((wx == 7) ? 1 : 0);
  const bf16* base = qkv + (size_t)w * WBLK;
  bf16* Pl = &P[wv][0];
  const float scale = 0.17677669529663689f;

  for (int hh = 0; hh < 3; ++hh) {
    int h = wv + hh * 4;
    const bf16* Q  = base + (size_t)h * HBLK;
    const bf16* Kp = base + (size_t)(NH + h) * HBLK;
    const bf16* Vt = base + (size_t)(2 * NH + h) * HBLK;
    const float* tb = tbl + (size_t)(cls * 12 + h) * 49 * 64;

    bf16x8 qa[4], kb[4];
#pragma unroll
    for (int t = 0; t < 4; ++t) {
      qa[t] = *(const bf16x8*)(Q  + (t * 16 + lr) * 32 + lg * 8);
      kb[t] = *(const bf16x8*)(Kp + (t * 16 + lr) * 32 + lg * 8);
    }
    f32x4 S[4][4] = {};
#pragma unroll
    for (int i = 0; i < 4; ++i)
#pragma unroll
      for (int j = 0; j < 4; ++j)
        S[i][j] = __builtin_amdgcn_mfma_f32_16x16x32_bf16(qa[i], kb[j], S[i][j], 0, 0, 0);

#pragma unroll
    for (int i = 0; i < 4; ++i) {
#pragma unroll
      for (int r = 0; r < 4; ++r) {
        int row = i * 16 + lg * 4 + r;
        const float* trow = tb + (row < 49 ? row : 0) * 64;
        float sv[4]; float m = -1e30f;
#pragma unroll
        for (int j = 0; j < 4; ++j) {
          float s = S[i][j][r] * scale + trow[j * 16 + lr];
          sv[j] = s;
          m = fmaxf(m, s);
        }
        m = fmaxf(m, __shfl_xor(m, 1));
        m = fmaxf(m, __shfl_xor(m, 2));
        m = fmaxf(m, __shfl_xor(m, 4));
        m = fmaxf(m, __shfl_xor(m, 8));
        float ev[4]; float sum = 0.f;
#pragma unroll
        for (int j = 0; j < 4; ++j) { ev[j] = __expf(sv[j] - m); sum += ev[j]; }
        sum += __shfl_xor(sum, 1);
        sum += __shfl_xor(sum, 2);
        sum += __shfl_xor(sum, 4);
        sum += __shfl_xor(sum, 8);
        float inv = 1.0f / sum;
#pragma unroll
        for (int j = 0; j < 4; ++j)
          Pl[row * 72 + j * 16 + lr] = __float2bfloat16(ev[j] * inv);
      }
    }

    bf16x8 vb[2][2];
#pragma unroll
    for (int kt = 0; kt < 2; ++kt)
#pragma unroll
      for (int cj = 0; cj < 2; ++cj)
        vb[kt][cj] = *(const bf16x8*)(Vt + (cj * 16 + lr) * 64 + kt * 32 + lg * 8);
    f32x4 O[4][2] = {};
#pragma unroll
    for (int i = 0; i < 4; ++i) {
#pragma unroll
      for (int kt = 0; kt < 2; ++kt) {
        bf16x8 pa = *(const bf16x8*)(Pl + (i * 16 + lr) * 72 + kt * 32 + lg * 8);
#pragma unroll
        for (int cj = 0; cj < 2; ++cj)
          O[i][cj] = __builtin_amdgcn_mfma_f32_16x16x32_bf16(pa, vb[kt][cj], O[i][cj], 0, 0, 0);
      }
    }
#pragma unroll
    for (int i = 0; i < 4; ++i)
#pragma unroll
      for (int cj = 0; cj < 2; ++cj)
#pragma unroll
        for (int r = 0; r < 4; ++r) {
          int n = i * 16 + lg * 4 + r;
          if (n < 49)
            attn_out[((size_t)w * 49 + n) * 384 + h * 32 + cj * 16 + lr] =
                __float2bfloat16(O[i][cj][r]);
        }
  }
}

extern "C" void kernel_launch(void* const* d_in, const int* in_sizes, int n_in,
                              void* d_out, int out_size, void* d_ws, size_t ws_size,
                              hipStream_t stream) {
  (void)in_sizes; (void)n_in; (void)out_size;
  const float* x     = (const float*)d_in[0];
  const float* g1    = (const float*)d_in[1];
  const float* be1   = (const float*)d_in[2];
  const float* w_qkv = (const float*)d_in[3];
  const float* b_qkv = (const float*)d_in[4];
  const float* rel   = (const float*)d_in[5];
  const float* w_pr  = (const float*)d_in[6];
  const float* b_pr  = (const float*)d_in[7];
  const float* g2    = (const float*)d_in[8];
  const float* be2   = (const float*)d_in[9];
  const float* w1    = (const float*)d_in[10];
  const float* b1    = (const float*)d_in[11];
  const float* w2    = (const float*)d_in[12];
  const float* b2    = (const float*)d_in[13];
  float* out = (float*)d_out;

  if (ws_size < 390070272u) return;

  char* ws = (char*)d_ws;
  bf16* wqkvT = (bf16*)(ws);                     // 1152 x 384
  bf16* wprT  = (bf16*)(ws + 884736);            // 384 x 384
  bf16* w1T   = (bf16*)(ws + 1179648);           // 1536 x 384
  bf16* w2T   = (bf16*)(ws + 2359296);           // 384 x 1536
  float* btbl = (float*)(ws + 3538944);          // 4 x 12 x 49 x 64 f32
  bf16* xw    = (bf16*)(ws + (4u << 20));        // 100352 x 384 bf16
  bf16* qkv   = (bf16*)(ws + (84u << 20));       // padded QKV (302 MB; reused)
  bf16* m_in  = qkv;                             // LN2 out reuses qkv head
  bf16* h1    = (bf16*)(ws + (164u << 20));      // 50176 x 1536 bf16 chunk

  cast_transpose<<<dim3((442368 + 255) / 256), 256, 0, stream>>>(w_qkv, wqkvT, 384, 1152);
  cast_transpose<<<dim3((147456 + 255) / 256), 256, 0, stream>>>(w_pr, wprT, 384, 384);
  cast_transpose<<<dim3((589824 + 255) / 256), 256, 0, stream>>>(w1, w1T, 384, 1536);
  cast_transpose<<<dim3((589824 + 255) / 256), 256, 0, stream>>>(w2, w2T, 1536, 384);

  build_bias<<<dim3((4 * 12 * 49 * 64 + 255) / 256), 256, 0, stream>>>(rel, btbl);

  zero_pads<<<dim3((NWIN * 3 * NH * 15 * HD + 255) / 256), 256, 0, stream>>>(qkv);

  ln_kernel<0><<<dim3(NTOK / 4), 256, 0, stream>>>(x, g1, be1, xw);

  // QKV: 9 bcols x 28 strips (strip = 14 tiles of 256 rows, 392 total)
  gemm_persist<0><<<dim3(252), 512, 0, stream>>>(xw, wqkvT, 392, 14, 28, 0,
                                                 b_qkv, nullptr, (void*)qkv);

  attn_kernel<<<dim3(NWIN), 256, 0, stream>>>(qkv, btbl, xw);

  // proj: 3 bcols x 84 strips (strip = 5 tiles, ragged)
  gemm_persist<1><<<dim3(252), 512, 0, stream>>>(xw, wprT, 392, 5, 84, 0,
                                                 b_pr, x, (void*)out);

  ln_kernel<1><<<dim3(NTOK / 4), 256, 0, stream>>>(out, g2, be2, m_in);

  for (int c = 0; c < 2; ++c) {
    // MLP1: 12 bcols x 21 strips (strip = 10 tiles over 196, ragged)
    gemm_persist<2><<<dim3(252), 512, 0, stream>>>(m_in + (size_t)c * 50176 * 384, w1T,
                                                   196, 10, 21, c * 50176,
                                                   b1, nullptr, (void*)h1);
    // MLP2: R8 structure (K=1536), 196 x 3 = 588
    gemm_mlp2<<<dim3(588), 512, 0, stream>>>(h1, w2T, 1536, 3, c * 50176, b2, out,
                                             (void*)out);
  }
}

// Round 14
// 948.696 us; speedup vs baseline: 1.0970x; 1.0365x over previous
//
#include <hip/hip_runtime.h>
#include <hip/hip_bf16.h>
#include <math.h>

typedef __attribute__((ext_vector_type(8))) short bf16x8;
typedef __attribute__((ext_vector_type(4))) short bf16x4;
typedef __attribute__((ext_vector_type(4))) float f32x4;
typedef __hip_bfloat16 bf16;

#define NH 12
#define HD 32
#define NPAD 64
#define NWIN 2048
#define NTOK 100352
#define HBLK (NPAD*HD)
#define WBLK (3*NH*HBLK)

typedef __attribute__((address_space(3))) const void cv3;

#define STR2(x) #x
#define DSR(dst, base, OFF)                                                  \
  asm volatile("ds_read_b128 %0, %1 offset:" STR2(OFF)                       \
               : "=v"(dst) : "v"(base))

__device__ inline float wave_sum(float v) {
#pragma unroll
  for (int off = 32; off; off >>= 1) v += __shfl_xor(v, off);
  return v;
}

__device__ inline void load_lds16(const bf16* g, bf16* l) {
  __builtin_amdgcn_global_load_lds((const __attribute__((address_space(1))) void*)g,
                                   (__attribute__((address_space(3))) void*)l, 16, 0, 0);
}

__device__ inline short bfbits(float f) {
  bf16 h = __float2bfloat16(f);
  return *(short*)&h;
}

// ---------------- weight cast + transpose
__global__ __launch_bounds__(256) void cast_transpose(const float* __restrict__ in,
                                                      bf16* __restrict__ out, int K, int N) {
  int e = blockIdx.x * 256 + threadIdx.x;
  if (e >= K * N) return;
  int n = e / K, k = e - n * K;
  out[e] = __float2bfloat16(in[k * N + n]);
}

// ---------------- zero the 15 pad rows of every (w, which, h) QKV block
__global__ __launch_bounds__(256) void zero_pads(bf16* __restrict__ qkv) {
  int idx = blockIdx.x * 256 + threadIdx.x;
  const int total = NWIN * 3 * NH * 15 * HD;
  if (idx >= total) return;
  int d = idx & 31; int rest = idx >> 5;
  int n = 49 + (rest % 15); rest /= 15;
  int h = rest % NH; rest /= NH;
  int which = rest % 3; int w = rest / 3;
  size_t base = (size_t)w * WBLK + (size_t)which * NH * HBLK + (size_t)h * HBLK;
  size_t addr = (which == 2) ? base + (size_t)d * NPAD + n : base + (size_t)n * HD + d;
  qkv[addr] = __float2bfloat16(0.0f);
}

// ---------------- bias+mask table: tbl[cls][h][row][64]
__global__ __launch_bounds__(256) void build_bias(const float* __restrict__ rel,
                                                  float* __restrict__ tbl) {
  int e = blockIdx.x * 256 + threadIdx.x;
  if (e >= 4 * 12 * 49 * 64) return;
  int col = e & 63; int t = e >> 6;
  int row = t % 49; t /= 49;
  int h = t % 12; int cls = t / 12;
  float v;
  if (col >= 49) {
    v = -1e30f;
  } else {
    int py = row / 7, px = row - py * 7;
    int qy = col / 7, qx = col - qy * 7;
    int ridx = (py - qy + 6) * 13 + (px - qx + 6);
    v = rel[ridx * 12 + h];
    int wy7 = cls >> 1, wx7 = cls & 1;
    int ly_r = wy7 ? (py < 4 ? 1 : 2) : 0;
    int lx_r = wx7 ? (px < 4 ? 1 : 2) : 0;
    int ly_c = wy7 ? (qy < 4 ? 1 : 2) : 0;
    int lx_c = wx7 ? (qx < 4 ? 1 : 2) : 0;
    if ((ly_r * 3 + lx_r) != (ly_c * 3 + lx_c)) v += -100.0f;
  }
  tbl[e] = v;
}

// ---------------- LayerNorm
template <int MODE>
__global__ __launch_bounds__(256) void ln_kernel(const float* __restrict__ x,
                                                 const float* __restrict__ g,
                                                 const float* __restrict__ be,
                                                 bf16* __restrict__ out) {
  int wv = threadIdx.x >> 6, lane = threadIdx.x & 63;
  int t = blockIdx.x * 4 + wv;
  size_t src;
  if (MODE == 0) {
    int w = t / 49, n = t - w * 49;
    int b = w >> 6, wi = w & 63;
    int wy = wi >> 3, wx = wi & 7;
    int py = n / 7, px = n - py * 7;
    int rr = wy * 7 + py, cc = wx * 7 + px;
    int ro = rr + 3; if (ro >= 56) ro -= 56;
    int co = cc + 3; if (co >= 56) co -= 56;
    src = (size_t)b * 3136 + ro * 56 + co;
  } else {
    src = (size_t)t;
  }
  const float2* row2 = (const float2*)(x + src * 384);
  float2 v[3]; float s = 0.f;
#pragma unroll
  for (int j = 0; j < 3; ++j) { v[j] = row2[lane + 64 * j]; s += v[j].x + v[j].y; }
  s = wave_sum(s);
  float mu = s * (1.f / 384.f);
  float q = 0.f;
#pragma unroll
  for (int j = 0; j < 3; ++j) {
    float dx = v[j].x - mu, dy = v[j].y - mu;
    q += dx * dx + dy * dy;
  }
  q = wave_sum(q);
  float rs = rsqrtf(q * (1.f / 384.f) + 1e-5f);
  uint* o = (uint*)(out + (size_t)t * 384);
  const float2* g2 = (const float2*)g;
  const float2* b2 = (const float2*)be;
#pragma unroll
  for (int j = 0; j < 3; ++j) {
    int c2 = lane + 64 * j;
    float2 gg = g2[c2], bb = b2[c2];
    float ox = (v[j].x - mu) * rs * gg.x + bb.x;
    float oy = (v[j].y - mu) * rs * gg.y + bb.y;
    o[c2] = (uint)(unsigned short)bfbits(ox) | ((uint)(unsigned short)bfbits(oy) << 16);
  }
}

// ---------------- UNIFIED GEMM: C = A(M x K) * B^T. Tile 128x128, 4 waves (2M x 2N,
// wave-tile 64x64), BK=32, 3-stage ring = 48 KB -> 3 BLOCKS/CU (cross-block TLP fills
// the lgkm/vmcnt/barrier windows; m114 mechanism). 2-deep prefetch, counted vmcnt(4)
// (4 gload_lds/wave/stage). Inline-asm ds_read_b128; split lgkm(3)/(0) + setprio.
// Swizzle (64B rows): LDS[row][s] = G[row][s ^ ((row>>1)&3)] in 16B granules (2-way free,
// verified R13). Swapped-operand MFMA -> thread holds 4 consecutive C-cols.
// Bijective chunked XCD swizzle.
// EPI: 0=QKV scatter, 1=proj+residual+reverse, 2=GELU->h1, 3=out=acc+b2+x1 -> d_out
template <int EPI>
__global__ __launch_bounds__(256, 3) void gemm128(const bf16* __restrict__ A,
                                                  const bf16* __restrict__ BT,
                                                  int K, int NCOL, int row0,
                                                  const float* __restrict__ bias,
                                                  const float* __restrict__ extra,
                                                  void* __restrict__ outp) {
  __shared__ __align__(16) bf16 As[3][128 * 32];   // 3 x 8 KB
  __shared__ __align__(16) bf16 Bs[3][128 * 32];   // 3 x 8 KB  (total 48 KB)
  int tid = threadIdx.x, lane = tid & 63, wv = tid >> 6;   // wv 0..3
  int wr = wv >> 1, wc = wv & 1;
  int lr = lane & 15, lg = lane >> 4;

  // bijective chunked XCD swizzle
  int nwg = gridDim.x;
  int bid = blockIdx.x;
  int xcd = bid & 7, li = bid >> 3;
  int qq = nwg >> 3, rr8 = nwg & 7;
  int start = xcd * qq + (xcd < rr8 ? xcd : rr8);
  int lin = start + li;
  int brow = lin / NCOL, bcol = lin - brow * NCOL;

  const bf16* Ab = A + (size_t)brow * 128 * K;
  const bf16* Bb = BT + (size_t)bcol * 128 * K;

  // staging: chunk = 16 rows x 32 cols (1 KB = one gload_lds). Wave wv stages A rows
  // [wv*32,+32) (2 chunks) + B rows [wv*32,+32) (2 chunks). Source granule pre-swizzled:
  // g = (lane&3) ^ ((srow>>1)&3), srow = lane>>2.
  int srow = lane >> 2;
  int scol8 = (((lane & 3) ^ ((srow >> 1) & 3)) << 3);
  const bf16* aS = Ab + (size_t)(wv * 32 + srow) * K + scol8;
  const bf16* bS = Bb + (size_t)(wv * 32 + srow) * K + scol8;

  f32x4 acc[4][4] = {};
  int nk = K >> 5;
  int koff = ((lg ^ ((lr >> 1) & 3)) << 3);

  // 4 gload_lds per wave per stage
#define STAGE(buf)                                                            \
  {                                                                           \
    load_lds16(aS, &As[buf][wv * 1024]);                                      \
    load_lds16(aS + (size_t)16 * K, &As[buf][wv * 1024 + 512]);               \
    load_lds16(bS, &Bs[buf][wv * 1024]);                                      \
    load_lds16(bS + (size_t)16 * K, &Bs[buf][wv * 1024 + 512]);               \
    aS += 32; bS += 32;                                                       \
  }

  STAGE(0);
  STAGE(1);
  asm volatile("s_waitcnt vmcnt(4)" ::: "memory");  // stage0 done; stage1 flying
  __builtin_amdgcn_s_barrier();

  for (int it = 0; it < nk; ++it) {
    int buf = it % 3;
    if (it + 2 < nk) STAGE((it + 2) % 3);
    cv3* pA = (cv3*)&As[buf][(wr * 64 + lr) * 32 + koff];
    cv3* pB = (cv3*)&Bs[buf][(wc * 64 + lr) * 32 + koff];
    bf16x8 a[4], b[4];
    DSR(a[0], pA, 0);
    DSR(b[0], pB, 0); DSR(b[1], pB, 1024); DSR(b[2], pB, 2048); DSR(b[3], pB, 3072);
    DSR(a[1], pA, 1024); DSR(a[2], pA, 2048); DSR(a[3], pA, 3072);
    asm volatile("s_waitcnt lgkmcnt(3)" ::: "memory");
    __builtin_amdgcn_sched_barrier(0);
    __builtin_amdgcn_s_setprio(1);
#pragma unroll
    for (int j = 0; j < 4; ++j)
      acc[0][j] = __builtin_amdgcn_mfma_f32_16x16x32_bf16(b[j], a[0], acc[0][j], 0, 0, 0);
    __builtin_amdgcn_s_setprio(0);
    asm volatile("s_waitcnt lgkmcnt(0)" ::: "memory");
    __builtin_amdgcn_sched_barrier(0);
    __builtin_amdgcn_s_setprio(1);
#pragma unroll
    for (int i = 1; i < 4; ++i)
#pragma unroll
      for (int j = 0; j < 4; ++j)
        acc[i][j] = __builtin_amdgcn_mfma_f32_16x16x32_bf16(b[j], a[i], acc[i][j], 0, 0, 0);
    __builtin_amdgcn_s_setprio(0);
    if (it + 1 < nk) {
      if (it + 2 < nk)
        asm volatile("s_waitcnt vmcnt(4)" ::: "memory");  // stage it+1 done; it+2 flying
      else
        asm volatile("s_waitcnt vmcnt(0)" ::: "memory");
      __builtin_amdgcn_s_barrier();
    }
  }
#undef STAGE

  // epilogue: C row = brow*128 + wr*64 + i*16 + lr; cols = bcol*128 + wc*64 + j*16 + lg*4+0..3
  float4 bias4[4];
#pragma unroll
  for (int j = 0; j < 4; ++j)
    bias4[j] = *(const float4*)(bias + bcol * 128 + wc * 64 + j * 16 + lg * 4);

#pragma unroll
  for (int i = 0; i < 4; ++i) {
    int lrow = brow * 128 + wr * 64 + i * 16 + lr;
    int grow = row0 + lrow;
    int w_ = 0, n_ = 0; size_t tok = 0;
    if (EPI == 0 || EPI == 1) {
      w_ = grow / 49; n_ = grow - w_ * 49;
      if (EPI == 1) {
        int b_ = w_ >> 6, wi = w_ & 63;
        int wy = wi >> 3, wx = wi & 7;
        int py = n_ / 7, px = n_ - py * 7;
        int r2 = wy * 7 + py, c2 = wx * 7 + px;
        int ro = r2 + 3; if (ro >= 56) ro -= 56;
        int co = c2 + 3; if (co >= 56) co -= 56;
        tok = (size_t)b_ * 3136 + ro * 56 + co;
      }
    }
#pragma unroll
    for (int j = 0; j < 4; ++j) {
      int col = bcol * 128 + wc * 64 + j * 16 + lg * 4;
      float v0 = acc[i][j][0] + bias4[j].x;
      float v1 = acc[i][j][1] + bias4[j].y;
      float v2 = acc[i][j][2] + bias4[j].z;
      float v3 = acc[i][j][3] + bias4[j].w;
      if (EPI == 0) {
        int which = (col >= 768) ? 2 : (col >= 384 ? 1 : 0);
        int cc = col - which * 384;
        int hh = cc >> 5, d0 = cc & 31;
        size_t base = (size_t)w_ * WBLK + (size_t)which * NH * HBLK + (size_t)hh * HBLK;
        if (which == 2) {
          bf16* vp = (bf16*)outp + base + (size_t)d0 * NPAD + n_;
          vp[0] = __float2bfloat16(v0);
          vp[NPAD] = __float2bfloat16(v1);
          vp[2 * NPAD] = __float2bfloat16(v2);
          vp[3 * NPAD] = __float2bfloat16(v3);
        } else {
          bf16x4 p = {bfbits(v0), bfbits(v1), bfbits(v2), bfbits(v3)};
          *(bf16x4*)((bf16*)outp + base + (size_t)n_ * HD + d0) = p;
        }
      } else if (EPI == 1) {
        size_t oidx = tok * 384 + col;
        float4 e = *(const float4*)(extra + oidx);
        float4 o = {v0 + e.x, v1 + e.y, v2 + e.z, v3 + e.w};
        *(float4*)((float*)outp + oidx) = o;
      } else if (EPI == 2) {
        float g0 = 0.5f * v0 * (1.0f + erff(v0 * 0.70710678118654752f));
        float g1 = 0.5f * v1 * (1.0f + erff(v1 * 0.70710678118654752f));
        float g2 = 0.5f * v2 * (1.0f + erff(v2 * 0.70710678118654752f));
        float g3 = 0.5f * v3 * (1.0f + erff(v3 * 0.70710678118654752f));
        bf16x4 p = {bfbits(g0), bfbits(g1), bfbits(g2), bfbits(g3)};
        *(bf16x4*)((bf16*)outp + (size_t)lrow * 1536 + col) = p;
      } else {
        size_t oidx = (size_t)grow * 384 + col;
        float4 e = *(const float4*)(extra + oidx);
        float4 o = {v0 + e.x, v1 + e.y, v2 + e.z, v3 + e.w};
        *(float4*)((float*)outp + oidx) = o;
      }
    }
  }
}

// ---------------- windowed attention: 1 block per window, 4 waves x 3 heads.
__global__ __launch_bounds__(256) void attn_kernel(const bf16* __restrict__ qkv,
                                                   const float* __restrict__ tbl,
                                                   bf16* __restrict__ attn_out) {
  __shared__ __align__(16) bf16 P[4][64 * 72];
  int wv = threadIdx.x >> 6, lane = threadIdx.x & 63;
  int lr = lane & 15, lg = lane >> 4;
  int w = blockIdx.x;
  int wi = w & 63, wy = wi >> 3, wx = wi & 7;
  int cls = ((wy == 7) ? 2 : 0) | ((wx == 7) ? 1 : 0);
  const bf16* base = qkv + (size_t)w * WBLK;
  bf16* Pl = &P[wv][0];
  const float scale = 0.17677669529663689f;

  for (int hh = 0; hh < 3; ++hh) {
    int h = wv + hh * 4;
    const bf16* Q  = base + (size_t)h * HBLK;
    const bf16* Kp = base + (size_t)(NH + h) * HBLK;
    const bf16* Vt = base + (size_t)(2 * NH + h) * HBLK;
    const float* tb = tbl + (size_t)(cls * 12 + h) * 49 * 64;

    bf16x8 qa[4], kb[4];
#pragma unroll
    for (int t = 0; t < 4; ++t) {
      qa[t] = *(const bf16x8*)(Q  + (t * 16 + lr) * 32 + lg * 8);
      kb[t] = *(const bf16x8*)(Kp + (t * 16 + lr) * 32 + lg * 8);
    }
    f32x4 S[4][4] = {};
#pragma unroll
    for (int i = 0; i < 4; ++i)
#pragma unroll
      for (int j = 0; j < 4; ++j)
        S[i][j] = __builtin_amdgcn_mfma_f32_16x16x32_bf16(qa[i], kb[j], S[i][j], 0, 0, 0);

#pragma unroll
    for (int i = 0; i < 4; ++i) {
#pragma unroll
      for (int r = 0; r < 4; ++r) {
        int row = i * 16 + lg * 4 + r;
        const float* trow = tb + (row < 49 ? row : 0) * 64;
        float sv[4]; float m = -1e30f;
#pragma unroll
        for (int j = 0; j < 4; ++j) {
          float s = S[i][j][r] * scale + trow[j * 16 + lr];
          sv[j] = s;
          m = fmaxf(m, s);
        }
        m = fmaxf(m, __shfl_xor(m, 1));
        m = fmaxf(m, __shfl_xor(m, 2));
        m = fmaxf(m, __shfl_xor(m, 4));
        m = fmaxf(m, __shfl_xor(m, 8));
        float ev[4]; float sum = 0.f;
#pragma unroll
        for (int j = 0; j < 4; ++j) { ev[j] = __expf(sv[j] - m); sum += ev[j]; }
        sum += __shfl_xor(sum, 1);
        sum += __shfl_xor(sum, 2);
        sum += __shfl_xor(sum, 4);
        sum += __shfl_xor(sum, 8);
        float inv = 1.0f / sum;
#pragma unroll
        for (int j = 0; j < 4; ++j)
          Pl[row * 72 + j * 16 + lr] = __float2bfloat16(ev[j] * inv);
      }
    }

    bf16x8 vb[2][2];
#pragma unroll
    for (int kt = 0; kt < 2; ++kt)
#pragma unroll
      for (int cj = 0; cj < 2; ++cj)
        vb[kt][cj] = *(const bf16x8*)(Vt + (cj * 16 + lr) * 64 + kt * 32 + lg * 8);
    f32x4 O[4][2] = {};
#pragma unroll
    for (int i = 0; i < 4; ++i) {
#pragma unroll
      for (int kt = 0; kt < 2; ++kt) {
        bf16x8 pa = *(const bf16x8*)(Pl + (i * 16 + lr) * 72 + kt * 32 + lg * 8);
#pragma unroll
        for (int cj = 0; cj < 2; ++cj)
          O[i][cj] = __builtin_amdgcn_mfma_f32_16x16x32_bf16(pa, vb[kt][cj], O[i][cj], 0, 0, 0);
      }
    }
#pragma unroll
    for (int i = 0; i < 4; ++i)
#pragma unroll
      for (int cj = 0; cj < 2; ++cj)
#pragma unroll
        for (int r = 0; r < 4; ++r) {
          int n = i * 16 + lg * 4 + r;
          if (n < 49)
            attn_out[((size_t)w * 49 + n) * 384 + h * 32 + cj * 16 + lr] =
                __float2bfloat16(O[i][cj][r]);
        }
  }
}

extern "C" void kernel_launch(void* const* d_in, const int* in_sizes, int n_in,
                              void* d_out, int out_size, void* d_ws, size_t ws_size,
                              hipStream_t stream) {
  (void)in_sizes; (void)n_in; (void)out_size;
  const float* x     = (const float*)d_in[0];
  const float* g1    = (const float*)d_in[1];
  const float* be1   = (const float*)d_in[2];
  const float* w_qkv = (const float*)d_in[3];
  const float* b_qkv = (const float*)d_in[4];
  const float* rel   = (const float*)d_in[5];
  const float* w_pr  = (const float*)d_in[6];
  const float* b_pr  = (const float*)d_in[7];
  const float* g2    = (const float*)d_in[8];
  const float* be2   = (const float*)d_in[9];
  const float* w1    = (const float*)d_in[10];
  const float* b1    = (const float*)d_in[11];
  const float* w2    = (const float*)d_in[12];
  const float* b2    = (const float*)d_in[13];
  float* out = (float*)d_out;

  if (ws_size < 390070272u) return;

  char* ws = (char*)d_ws;
  bf16* wqkvT = (bf16*)(ws);                     // 1152 x 384
  bf16* wprT  = (bf16*)(ws + 884736);            // 384 x 384
  bf16* w1T   = (bf16*)(ws + 1179648);           // 1536 x 384
  bf16* w2T   = (bf16*)(ws + 2359296);           // 384 x 1536
  float* btbl = (float*)(ws + 3538944);          // 4 x 12 x 49 x 64 f32
  bf16* xw    = (bf16*)(ws + (4u << 20));        // 100352 x 384 bf16
  bf16* qkv   = (bf16*)(ws + (84u << 20));       // padded QKV (302 MB)
  bf16* m_in  = qkv;                             // LN2 out reuses qkv head
  bf16* h1    = (bf16*)(ws + (164u << 20));      // 50176 x 1536 bf16 chunk

  cast_transpose<<<dim3((442368 + 255) / 256), 256, 0, stream>>>(w_qkv, wqkvT, 384, 1152);
  cast_transpose<<<dim3((147456 + 255) / 256), 256, 0, stream>>>(w_pr, wprT, 384, 384);
  cast_transpose<<<dim3((589824 + 255) / 256), 256, 0, stream>>>(w1, w1T, 384, 1536);
  cast_transpose<<<dim3((589824 + 255) / 256), 256, 0, stream>>>(w2, w2T, 1536, 384);

  build_bias<<<dim3((4 * 12 * 49 * 64 + 255) / 256), 256, 0, stream>>>(rel, btbl);

  zero_pads<<<dim3((NWIN * 3 * NH * 15 * HD + 255) / 256), 256, 0, stream>>>(qkv);

  ln_kernel<0><<<dim3(NTOK / 4), 256, 0, stream>>>(x, g1, be1, xw);

  // QKV: 784 brows x 9 bcols = 7056
  gemm128<0><<<dim3(7056), 256, 0, stream>>>(xw, wqkvT, 384, 9, 0, b_qkv, nullptr,
                                             (void*)qkv);

  attn_kernel<<<dim3(NWIN), 256, 0, stream>>>(qkv, btbl, xw);

  // proj: 784 x 3 = 2352
  gemm128<1><<<dim3(2352), 256, 0, stream>>>(xw, wprT, 384, 3, 0, b_pr, x, (void*)out);

  ln_kernel<1><<<dim3(NTOK / 4), 256, 0, stream>>>(out, g2, be2, m_in);

  for (int c = 0; c < 2; ++c) {
    // MLP1: 392 x 12 = 4704
    gemm128<2><<<dim3(4704), 256, 0, stream>>>(m_in + (size_t)c * 50176 * 384, w1T, 384,
                                               12, c * 50176, b1, nullptr, (void*)h1);
    // MLP2: 392 x 3 = 1176 (K=1536)
    gemm128<3><<<dim3(1176), 256, 0, stream>>>(h1, w2T, 1536, 3, c * 50176, b2, out,
                                               (void*)out);
  }
}